// Round 2
// baseline (11571.058 us; speedup 1.0000x reference)
//
#include <hip/hip_runtime.h>

#define D 300
#define NGR 256
#define NL 5
#define NC 128
#define BN_EPS 1e-5f

__device__ __forceinline__ void atomAdd(float* p, float v) { unsafeAtomicAdd(p, v); }

// ---------------------------------------------------------------------------
// offsets: off[g] = lower_bound(batch, g), g in [0,256]; batch sorted int32
// ---------------------------------------------------------------------------
__global__ void offsets_kernel(const int* __restrict__ batch, int* __restrict__ off, int N) {
    int g = threadIdx.x;
    if (g > NGR) return;
    int lo = 0, hi = N;
    while (lo < hi) {
        int mid = (lo + hi) >> 1;
        if (batch[mid] < g) lo = mid + 1; else hi = mid;
    }
    off[g] = lo;
}

// ---------------------------------------------------------------------------
// pool: pooled_l[g][c] += sum over node-chunk of H[r][c]  (grid: NGR x 4)
// ---------------------------------------------------------------------------
__global__ __launch_bounds__(320)
void pool_kernel(const float* __restrict__ H, const int* __restrict__ off,
                 float* __restrict__ pooled_l) {
    int c = threadIdx.x;
    if (c >= D) return;
    int g = blockIdx.x;
    int chunk = blockIdx.y;
    int r0 = off[g], r1 = off[g + 1];
    int len = r1 - r0;
    int per = (len + 3) >> 2;
    int a = r0 + chunk * per;
    int b = min(a + per, r1);
    float s = 0.f;
    for (int r = a; r < b; ++r) s += H[r * D + c];
    if (b > a) atomAdd(&pooled_l[g * D + c], s);
}

// ---------------------------------------------------------------------------
// scatter: Z[dst] += H[src] over edges (Z pre-initialized to H)
// one thread per (edge, 4-col group)
// ---------------------------------------------------------------------------
__global__ __launch_bounds__(256)
void scatter_kernel(const float* __restrict__ H, float* __restrict__ Z,
                    const int* __restrict__ ei, int E) {
    int idx = blockIdx.x * 256 + threadIdx.x;
    if (idx >= E * 75) return;
    int e = idx / 75;
    int c = (idx - e * 75) * 4;
    int src = ei[e];
    int dst = ei[E + e];
    const float4 v = *(const float4*)(H + src * D + c);
    float* zp = Z + dst * D + c;
    atomAdd(zp + 0, v.x);
    atomAdd(zp + 1, v.y);
    atomAdd(zp + 2, v.z);
    atomAdd(zp + 3, v.w);
}

// ---------------------------------------------------------------------------
// GEMM: C = op(A) @ W + bias ; A is MxD, W is DxD row-major, C MxD
// APPLY: op(a)[m][k] = relu(a*scale[k] + shift[k])  (fused BN1+ReLU)
// 64x64 tile, K-chunk 16, 256 threads, 4x4 microtile
// ---------------------------------------------------------------------------
template<bool APPLY>
__global__ __launch_bounds__(256)
void gemm_kernel(const float* __restrict__ A, const float* __restrict__ W,
                 const float* __restrict__ bias, const float* __restrict__ scsh,
                 float* __restrict__ Cmat, int M) {
    __shared__ float As[16][68];   // stride 68: 16B-aligned rows
    __shared__ float Bs[16][68];
    __shared__ float s_sc[304], s_sh[304];

    const int tid = threadIdx.x;
    const int m0 = blockIdx.x * 64;
    const int n0 = blockIdx.y * 64;

    if (APPLY) {
        for (int c = tid; c < D; c += 256) { s_sc[c] = scsh[c]; s_sh[c] = scsh[D + c]; }
    }
    __syncthreads();

    const int tx = tid & 15, ty = tid >> 4;
    const int am = tid >> 2;          // 0..63 : A row within tile
    const int ak = (tid & 3) << 2;    // 0,4,8,12 : A k within chunk
    const int bk = tid >> 4;          // 0..15 : B k within chunk
    const int bn4 = (tid & 15) << 2;  // 0..60 : B col within tile

    float acc[4][4] = {};

    for (int k0 = 0; k0 < D; k0 += 16) {
        float4 va = make_float4(0.f, 0.f, 0.f, 0.f);
        {
            int m = m0 + am;
            int k = k0 + ak;
            if (m < M && k + 3 < D) {
                va = *(const float4*)(A + m * D + k);
                if (APPLY) {
                    va.x = fmaxf(fmaf(va.x, s_sc[k],     s_sh[k]),     0.f);
                    va.y = fmaxf(fmaf(va.y, s_sc[k + 1], s_sh[k + 1]), 0.f);
                    va.z = fmaxf(fmaf(va.z, s_sc[k + 2], s_sh[k + 2]), 0.f);
                    va.w = fmaxf(fmaf(va.w, s_sc[k + 3], s_sh[k + 3]), 0.f);
                }
            }
        }
        float4 vb = make_float4(0.f, 0.f, 0.f, 0.f);
        {
            int k = k0 + bk;
            int n = n0 + bn4;
            if (k < D && n + 3 < D) vb = *(const float4*)(W + k * D + n);
        }
        As[ak + 0][am] = va.x;
        As[ak + 1][am] = va.y;
        As[ak + 2][am] = va.z;
        As[ak + 3][am] = va.w;
        *(float4*)&Bs[bk][bn4] = vb;
        __syncthreads();

        #pragma unroll
        for (int kk = 0; kk < 16; ++kk) {
            float4 a4 = *(const float4*)&As[kk][ty << 2];
            float4 b4 = *(const float4*)&Bs[kk][tx << 2];
            float av[4] = {a4.x, a4.y, a4.z, a4.w};
            float bv[4] = {b4.x, b4.y, b4.z, b4.w};
            #pragma unroll
            for (int i = 0; i < 4; ++i)
                #pragma unroll
                for (int j = 0; j < 4; ++j)
                    acc[i][j] = fmaf(av[i], bv[j], acc[i][j]);
        }
        __syncthreads();
    }

    int nn = n0 + (tx << 2);
    if (nn + 3 < D) {
        float4 bia = *(const float4*)(bias + nn);
        #pragma unroll
        for (int i = 0; i < 4; ++i) {
            int m = m0 + (ty << 2) + i;
            if (m < M) {
                float4 r;
                r.x = acc[i][0] + bia.x;
                r.y = acc[i][1] + bia.y;
                r.z = acc[i][2] + bia.z;
                r.w = acc[i][3] + bia.w;
                *(float4*)(Cmat + m * D + nn) = r;
            }
        }
    }
}

// ---------------------------------------------------------------------------
// column stats: sums[c] += sum(T[:,c]), sums[D+c] += sum(T[:,c]^2)
// ---------------------------------------------------------------------------
__global__ __launch_bounds__(320)
void colstats_kernel(const float* __restrict__ T, float* __restrict__ sums, int M) {
    int c = threadIdx.x;
    if (c >= D) return;
    int nb = gridDim.x;
    int per = (M + nb - 1) / nb;
    int r0 = blockIdx.x * per;
    int r1 = min(r0 + per, M);
    float s = 0.f, ss = 0.f;
    for (int r = r0; r < r1; ++r) {
        float v = T[r * D + c];
        s += v;
        ss = fmaf(v, v, ss);
    }
    atomAdd(&sums[c], s);
    atomAdd(&sums[D + c], ss);
}

// ---------------------------------------------------------------------------
// BN finalize: scale = g / sqrt(var+eps), shift = be - mu*scale
// ---------------------------------------------------------------------------
__global__ void bnfin_kernel(const float* __restrict__ sums, const float* __restrict__ g,
                             const float* __restrict__ be, float* __restrict__ scsh, float invN) {
    int c = threadIdx.x;
    if (c >= D) return;
    float mu = sums[c] * invN;
    float var = sums[D + c] * invN - mu * mu;
    float s = g[c] / sqrtf(var + BN_EPS);
    scsh[c] = s;
    scsh[D + c] = fmaf(-mu, s, be[c]);
}

// ---------------------------------------------------------------------------
// BN2 apply + ReLU: Z in-place, also write H (= next-layer h and scatter init)
// ---------------------------------------------------------------------------
__global__ __launch_bounds__(256)
void bnapply_kernel(float* __restrict__ Z, float* __restrict__ H,
                    const float* __restrict__ scsh, int n4) {
    int i = blockIdx.x * 256 + threadIdx.x;
    if (i >= n4) return;
    int base = i * 4;
    int c = base % D;   // D divisible by 4 -> no wrap within float4
    float4 v = *(const float4*)(Z + base);
    v.x = fmaxf(fmaf(v.x, scsh[c],     scsh[D + c]),     0.f);
    v.y = fmaxf(fmaf(v.y, scsh[c + 1], scsh[D + c + 1]), 0.f);
    v.z = fmaxf(fmaf(v.z, scsh[c + 2], scsh[D + c + 2]), 0.f);
    v.w = fmaxf(fmaf(v.w, scsh[c + 3], scsh[D + c + 3]), 0.f);
    *(float4*)(Z + base) = v;
    *(float4*)(H + base) = v;
}

// ---------------------------------------------------------------------------
// readout: out[g][c] = inv[g] * sum_l (pooled[l][g][:] . fcW[l][:,c]) + sum_l fcb[l][c]
// ---------------------------------------------------------------------------
__global__ __launch_bounds__(128)
void readout_kernel(const float* __restrict__ pooled, const int* __restrict__ off,
                    const float* __restrict__ fcW, const float* __restrict__ fcb,
                    float* __restrict__ out) {
    __shared__ float sp[8][D];
    int c = threadIdx.x;
    int g0 = blockIdx.x * 8;
    float acc[8] = {0.f, 0.f, 0.f, 0.f, 0.f, 0.f, 0.f, 0.f};
    for (int l = 0; l < NL + 1; ++l) {
        __syncthreads();
        for (int i = c; i < 8 * D; i += 128) {
            int gg = i / D, k = i - gg * D;
            sp[gg][k] = pooled[(l * NGR + g0 + gg) * D + k];
        }
        __syncthreads();
        for (int k = 0; k < D; ++k) {
            float w = fcW[(l * D + k) * NC + c];
            #pragma unroll
            for (int gg = 0; gg < 8; ++gg) acc[gg] = fmaf(sp[gg][k], w, acc[gg]);
        }
    }
    float bsum = 0.f;
    for (int l = 0; l < NL + 1; ++l) bsum += fcb[l * NC + c];
    for (int gg = 0; gg < 8; ++gg) {
        int g = g0 + gg;
        float cnt = (float)(off[g + 1] - off[g]);
        float inv = 1.0f / fmaxf(cnt, 1.0f);
        out[g * NC + c] = fmaf(acc[gg], inv, bsum);
    }
}

// ---------------------------------------------------------------------------
extern "C" void kernel_launch(void* const* d_in, const int* in_sizes, int n_in,
                              void* d_out, int out_size, void* d_ws, size_t ws_size,
                              hipStream_t stream) {
    const float* x       = (const float*)d_in[0];
    const int*   ei      = (const int*)d_in[1];     // int32 on device
    const int*   batch   = (const int*)d_in[2];     // int32 on device
    const float* W1  = (const float*)d_in[3];
    const float* b1  = (const float*)d_in[4];
    const float* g1  = (const float*)d_in[5];
    const float* be1 = (const float*)d_in[6];
    const float* W2  = (const float*)d_in[7];
    const float* b2  = (const float*)d_in[8];
    const float* bng = (const float*)d_in[9];
    const float* bnb = (const float*)d_in[10];
    const float* fcW = (const float*)d_in[11];
    const float* fcb = (const float*)d_in[12];
    float* out = (float*)d_out;

    const int N = in_sizes[0] / D;   // 50000
    const int E = in_sizes[1] / 2;   // 400000
    const size_t ND = (size_t)N * D;

    // 2-buffer scheme: h and z ping-pong; ~122 MB total
    float* h      = (float*)d_ws;
    float* z      = h + ND;
    float* pooled = z + ND;                                  // (NL+1)*NGR*D
    float* stats  = pooled + (size_t)(NL + 1) * NGR * D;     // 2*D
    float* sc1    = stats + 2 * D;                           // 2*D
    float* sc2    = sc1 + 2 * D;                             // 2*D
    int*   off    = (int*)(sc2 + 2 * D);                     // NGR+1

    hipMemcpyAsync(h, x, ND * sizeof(float), hipMemcpyDeviceToDevice, stream);
    hipMemcpyAsync(z, x, ND * sizeof(float), hipMemcpyDeviceToDevice, stream);
    hipMemsetAsync(pooled, 0, (size_t)(NL + 1) * NGR * D * sizeof(float), stream);
    offsets_kernel<<<1, 320, 0, stream>>>(batch, off, N);

    dim3 gemm_grid((N + 63) / 64, (D + 63) / 64);
    int scatter_blocks = (E * 75 + 255) / 256;
    int n4 = (int)(ND / 4);
    int bnapply_blocks = (n4 + 255) / 256;
    float invN = 1.0f / (float)N;

    for (int l = 0; l < NL; ++l) {
        pool_kernel<<<dim3(NGR, 4), 320, 0, stream>>>(h, off, pooled + (size_t)l * NGR * D);
        scatter_kernel<<<scatter_blocks, 256, 0, stream>>>(h, z, ei, E);
        // GEMM1: z -> h (h free after pool+scatter)
        gemm_kernel<false><<<gemm_grid, 256, 0, stream>>>(
            z, W1 + (size_t)l * D * D, b1 + l * D, sc1, h, N);
        hipMemsetAsync(stats, 0, 2 * D * sizeof(float), stream);
        colstats_kernel<<<128, 320, 0, stream>>>(h, stats, N);
        bnfin_kernel<<<1, 320, 0, stream>>>(stats, g1 + l * D, be1 + l * D, sc1, invN);
        // GEMM2 (BN1+ReLU fused on A-load): h -> z
        gemm_kernel<true><<<gemm_grid, 256, 0, stream>>>(
            h, W2 + (size_t)l * D * D, b2 + l * D, sc1, z, N);
        hipMemsetAsync(stats, 0, 2 * D * sizeof(float), stream);
        colstats_kernel<<<128, 320, 0, stream>>>(z, stats, N);
        bnfin_kernel<<<1, 320, 0, stream>>>(stats, bng + l * D, bnb + l * D, sc2, invN);
        // BN2+ReLU: z in place, h := same value (next h AND next scatter-init)
        bnapply_kernel<<<bnapply_blocks, 256, 0, stream>>>(z, h, sc2, n4);
    }
    pool_kernel<<<dim3(NGR, 4), 320, 0, stream>>>(h, off, pooled + (size_t)NL * NGR * D);
    readout_kernel<<<NGR / 8, 128, 0, stream>>>(pooled, off, fcW, fcb, out);
}

// Round 3
// 3586.885 us; speedup vs baseline: 3.2259x; 3.2259x over previous
//
#include <hip/hip_runtime.h>

#define D 300
#define NGR 256
#define NL 5
#define NC 128
#define BN_EPS 1e-5f

__device__ __forceinline__ void atomAdd(float* p, float v) { unsafeAtomicAdd(p, v); }

// ---------------------------------------------------------------------------
// offsets: off[g] = lower_bound(batch, g), g in [0,256]; batch sorted int32
// ---------------------------------------------------------------------------
__global__ void offsets_kernel(const int* __restrict__ batch, int* __restrict__ off, int N) {
    int g = threadIdx.x;
    if (g > NGR) return;
    int lo = 0, hi = N;
    while (lo < hi) {
        int mid = (lo + hi) >> 1;
        if (batch[mid] < g) lo = mid + 1; else hi = mid;
    }
    off[g] = lo;
}

// ---------------------------------------------------------------------------
// CSR build: in-degree histogram -> exclusive scan -> slot fill
// ---------------------------------------------------------------------------
__global__ __launch_bounds__(256)
void deg_kernel(const int* __restrict__ ei, int* __restrict__ deg, int E) {
    int e = blockIdx.x * 256 + threadIdx.x;
    if (e < E) atomicAdd(&deg[ei[E + e]], 1);
}

__global__ __launch_bounds__(1024)
void scan_kernel(const int* __restrict__ deg, int* __restrict__ rowptr, int N) {
    __shared__ int part[1024];
    int t = threadIdx.x;
    int per = (N + 1023) / 1024;
    int a = t * per, b = min(a + per, N);
    int s = 0;
    for (int i = a; i < b; ++i) s += deg[i];
    part[t] = s;
    __syncthreads();
    for (int off = 1; off < 1024; off <<= 1) {
        int v = (t >= off) ? part[t - off] : 0;
        __syncthreads();
        part[t] += v;
        __syncthreads();
    }
    int base = (t == 0) ? 0 : part[t - 1];
    for (int i = a; i < b; ++i) { rowptr[i] = base; base += deg[i]; }
    if (t == 1023) rowptr[N] = base;
}

__global__ __launch_bounds__(256)
void fill_kernel(const int* __restrict__ ei, const int* __restrict__ rowptr,
                 int* __restrict__ cursor, int* __restrict__ col, int E) {
    int e = blockIdx.x * 256 + threadIdx.x;
    if (e >= E) return;
    int src = ei[e];
    int dst = ei[E + e];
    int pos = atomicAdd(&cursor[dst], 1);
    col[rowptr[dst] + pos] = src;
}

// ---------------------------------------------------------------------------
// gather (pull-mode aggregation): Z[i] = H[i] + sum_{j in N(i)} H[j]
// one thread per (node, float4 column group); no float atomics
// ---------------------------------------------------------------------------
__global__ __launch_bounds__(256)
void gather_kernel(const float* __restrict__ H, float* __restrict__ Z,
                   const int* __restrict__ rowptr, const int* __restrict__ col, int N) {
    int idx = blockIdx.x * 256 + threadIdx.x;
    if (idx >= N * 75) return;
    int node = idx / 75;
    int c = (idx - node * 75) * 4;
    int s = rowptr[node], e = rowptr[node + 1];
    float4 acc = *(const float4*)(H + (size_t)node * D + c);   // self term
    for (int j = s; j < e; ++j) {
        int src = col[j];
        const float4 v = *(const float4*)(H + (size_t)src * D + c);
        acc.x += v.x; acc.y += v.y; acc.z += v.z; acc.w += v.w;
    }
    *(float4*)(Z + (size_t)node * D + c) = acc;
}

// ---------------------------------------------------------------------------
// pool: pooled_l[g][c] += sum over node-chunk of H[r][c]  (grid: NGR x 4)
// ---------------------------------------------------------------------------
__global__ __launch_bounds__(320)
void pool_kernel(const float* __restrict__ H, const int* __restrict__ off,
                 float* __restrict__ pooled_l) {
    int c = threadIdx.x;
    if (c >= D) return;
    int g = blockIdx.x;
    int chunk = blockIdx.y;
    int r0 = off[g], r1 = off[g + 1];
    int len = r1 - r0;
    int per = (len + 3) >> 2;
    int a = r0 + chunk * per;
    int b = min(a + per, r1);
    float s = 0.f;
    for (int r = a; r < b; ++r) s += H[r * D + c];
    if (b > a) atomAdd(&pooled_l[g * D + c], s);
}

// ---------------------------------------------------------------------------
// GEMM: C = op(A) @ W + bias ; A is MxD, W is DxD row-major, C MxD
// APPLY: op(a)[m][k] = relu(a*scale[k] + shift[k])  (fused BN1+ReLU)
// 64x64 tile, K-chunk 16, 256 threads, 4x4 microtile
// ---------------------------------------------------------------------------
template<bool APPLY>
__global__ __launch_bounds__(256)
void gemm_kernel(const float* __restrict__ A, const float* __restrict__ W,
                 const float* __restrict__ bias, const float* __restrict__ scsh,
                 float* __restrict__ Cmat, int M) {
    __shared__ float As[16][68];
    __shared__ float Bs[16][68];
    __shared__ float s_sc[304], s_sh[304];

    const int tid = threadIdx.x;
    const int m0 = blockIdx.x * 64;
    const int n0 = blockIdx.y * 64;

    if (APPLY) {
        for (int c = tid; c < D; c += 256) { s_sc[c] = scsh[c]; s_sh[c] = scsh[D + c]; }
    }
    __syncthreads();

    const int tx = tid & 15, ty = tid >> 4;
    const int am = tid >> 2;
    const int ak = (tid & 3) << 2;
    const int bk = tid >> 4;
    const int bn4 = (tid & 15) << 2;

    float acc[4][4] = {};

    for (int k0 = 0; k0 < D; k0 += 16) {
        float4 va = make_float4(0.f, 0.f, 0.f, 0.f);
        {
            int m = m0 + am;
            int k = k0 + ak;
            if (m < M && k + 3 < D) {
                va = *(const float4*)(A + m * D + k);
                if (APPLY) {
                    va.x = fmaxf(fmaf(va.x, s_sc[k],     s_sh[k]),     0.f);
                    va.y = fmaxf(fmaf(va.y, s_sc[k + 1], s_sh[k + 1]), 0.f);
                    va.z = fmaxf(fmaf(va.z, s_sc[k + 2], s_sh[k + 2]), 0.f);
                    va.w = fmaxf(fmaf(va.w, s_sc[k + 3], s_sh[k + 3]), 0.f);
                }
            }
        }
        float4 vb = make_float4(0.f, 0.f, 0.f, 0.f);
        {
            int k = k0 + bk;
            int n = n0 + bn4;
            if (k < D && n + 3 < D) vb = *(const float4*)(W + k * D + n);
        }
        As[ak + 0][am] = va.x;
        As[ak + 1][am] = va.y;
        As[ak + 2][am] = va.z;
        As[ak + 3][am] = va.w;
        *(float4*)&Bs[bk][bn4] = vb;
        __syncthreads();

        #pragma unroll
        for (int kk = 0; kk < 16; ++kk) {
            float4 a4 = *(const float4*)&As[kk][ty << 2];
            float4 b4 = *(const float4*)&Bs[kk][tx << 2];
            float av[4] = {a4.x, a4.y, a4.z, a4.w};
            float bv[4] = {b4.x, b4.y, b4.z, b4.w};
            #pragma unroll
            for (int i = 0; i < 4; ++i)
                #pragma unroll
                for (int j = 0; j < 4; ++j)
                    acc[i][j] = fmaf(av[i], bv[j], acc[i][j]);
        }
        __syncthreads();
    }

    int nn = n0 + (tx << 2);
    if (nn + 3 < D) {
        float4 bia = *(const float4*)(bias + nn);
        #pragma unroll
        for (int i = 0; i < 4; ++i) {
            int m = m0 + (ty << 2) + i;
            if (m < M) {
                float4 r;
                r.x = acc[i][0] + bia.x;
                r.y = acc[i][1] + bia.y;
                r.z = acc[i][2] + bia.z;
                r.w = acc[i][3] + bia.w;
                *(float4*)(Cmat + m * D + nn) = r;
            }
        }
    }
}

// ---------------------------------------------------------------------------
// column stats: sums[c] += sum(T[:,c]), sums[D+c] += sum(T[:,c]^2)
// ---------------------------------------------------------------------------
__global__ __launch_bounds__(320)
void colstats_kernel(const float* __restrict__ T, float* __restrict__ sums, int M) {
    int c = threadIdx.x;
    if (c >= D) return;
    int nb = gridDim.x;
    int per = (M + nb - 1) / nb;
    int r0 = blockIdx.x * per;
    int r1 = min(r0 + per, M);
    float s = 0.f, ss = 0.f;
    for (int r = r0; r < r1; ++r) {
        float v = T[r * D + c];
        s += v;
        ss = fmaf(v, v, ss);
    }
    atomAdd(&sums[c], s);
    atomAdd(&sums[D + c], ss);
}

// ---------------------------------------------------------------------------
// BN finalize: scale = g / sqrt(var+eps), shift = be - mu*scale
// ---------------------------------------------------------------------------
__global__ void bnfin_kernel(const float* __restrict__ sums, const float* __restrict__ g,
                             const float* __restrict__ be, float* __restrict__ scsh, float invN) {
    int c = threadIdx.x;
    if (c >= D) return;
    float mu = sums[c] * invN;
    float var = sums[D + c] * invN - mu * mu;
    float s = g[c] / sqrtf(var + BN_EPS);
    scsh[c] = s;
    scsh[D + c] = fmaf(-mu, s, be[c]);
}

// ---------------------------------------------------------------------------
// BN2 apply + ReLU: read Z, write H only (gather fully overwrites Z next layer)
// ---------------------------------------------------------------------------
__global__ __launch_bounds__(256)
void bnapply_kernel(const float* __restrict__ Z, float* __restrict__ H,
                    const float* __restrict__ scsh, int n4) {
    int i = blockIdx.x * 256 + threadIdx.x;
    if (i >= n4) return;
    int base = i * 4;
    int c = base % D;
    float4 v = *(const float4*)(Z + base);
    v.x = fmaxf(fmaf(v.x, scsh[c],     scsh[D + c]),     0.f);
    v.y = fmaxf(fmaf(v.y, scsh[c + 1], scsh[D + c + 1]), 0.f);
    v.z = fmaxf(fmaf(v.z, scsh[c + 2], scsh[D + c + 2]), 0.f);
    v.w = fmaxf(fmaf(v.w, scsh[c + 3], scsh[D + c + 3]), 0.f);
    *(float4*)(H + base) = v;
}

// ---------------------------------------------------------------------------
// readout
// ---------------------------------------------------------------------------
__global__ __launch_bounds__(128)
void readout_kernel(const float* __restrict__ pooled, const int* __restrict__ off,
                    const float* __restrict__ fcW, const float* __restrict__ fcb,
                    float* __restrict__ out) {
    __shared__ float sp[8][D];
    int c = threadIdx.x;
    int g0 = blockIdx.x * 8;
    float acc[8] = {0.f, 0.f, 0.f, 0.f, 0.f, 0.f, 0.f, 0.f};
    for (int l = 0; l < NL + 1; ++l) {
        __syncthreads();
        for (int i = c; i < 8 * D; i += 128) {
            int gg = i / D, k = i - gg * D;
            sp[gg][k] = pooled[(l * NGR + g0 + gg) * D + k];
        }
        __syncthreads();
        for (int k = 0; k < D; ++k) {
            float w = fcW[(l * D + k) * NC + c];
            #pragma unroll
            for (int gg = 0; gg < 8; ++gg) acc[gg] = fmaf(sp[gg][k], w, acc[gg]);
        }
    }
    float bsum = 0.f;
    for (int l = 0; l < NL + 1; ++l) bsum += fcb[l * NC + c];
    for (int gg = 0; gg < 8; ++gg) {
        int g = g0 + gg;
        float cnt = (float)(off[g + 1] - off[g]);
        float inv = 1.0f / fmaxf(cnt, 1.0f);
        out[g * NC + c] = fmaf(acc[gg], inv, bsum);
    }
}

// ---------------------------------------------------------------------------
extern "C" void kernel_launch(void* const* d_in, const int* in_sizes, int n_in,
                              void* d_out, int out_size, void* d_ws, size_t ws_size,
                              hipStream_t stream) {
    const float* x       = (const float*)d_in[0];
    const int*   ei      = (const int*)d_in[1];
    const int*   batch   = (const int*)d_in[2];
    const float* W1  = (const float*)d_in[3];
    const float* b1  = (const float*)d_in[4];
    const float* g1  = (const float*)d_in[5];
    const float* be1 = (const float*)d_in[6];
    const float* W2  = (const float*)d_in[7];
    const float* b2  = (const float*)d_in[8];
    const float* bng = (const float*)d_in[9];
    const float* bnb = (const float*)d_in[10];
    const float* fcW = (const float*)d_in[11];
    const float* fcb = (const float*)d_in[12];
    float* out = (float*)d_out;

    const int N = in_sizes[0] / D;   // 50000
    const int E = in_sizes[1] / 2;   // 400000
    const size_t ND = (size_t)N * D;

    float* h      = (float*)d_ws;
    float* z      = h + ND;
    float* pooled = z + ND;                                  // (NL+1)*NGR*D
    float* stats  = pooled + (size_t)(NL + 1) * NGR * D;     // 2*D
    float* sc1    = stats + 2 * D;                           // 2*D
    float* sc2    = sc1 + 2 * D;                             // 2*D
    int*   off    = (int*)(sc2 + 2 * D);                     // NGR+1
    int*   rowptr = off + NGR + 1;                           // N+1
    int*   cursor = rowptr + N + 1;                          // N
    int*   col    = cursor + N;                              // E

    hipMemcpyAsync(h, x, ND * sizeof(float), hipMemcpyDeviceToDevice, stream);
    hipMemsetAsync(pooled, 0, (size_t)(NL + 1) * NGR * D * sizeof(float), stream);
    offsets_kernel<<<1, 320, 0, stream>>>(batch, off, N);

    // ---- CSR build (once; edge_index constant across layers) ----
    hipMemsetAsync(cursor, 0, N * sizeof(int), stream);
    deg_kernel<<<(E + 255) / 256, 256, 0, stream>>>(ei, cursor, E);
    scan_kernel<<<1, 1024, 0, stream>>>(cursor, rowptr, N);
    hipMemsetAsync(cursor, 0, N * sizeof(int), stream);
    fill_kernel<<<(E + 255) / 256, 256, 0, stream>>>(ei, rowptr, cursor, col, E);

    dim3 gemm_grid((N + 63) / 64, (D + 63) / 64);
    int gather_blocks = (N * 75 + 255) / 256;
    int n4 = (int)(ND / 4);
    int bnapply_blocks = (n4 + 255) / 256;
    float invN = 1.0f / (float)N;

    for (int l = 0; l < NL; ++l) {
        pool_kernel<<<dim3(NGR, 4), 320, 0, stream>>>(h, off, pooled + (size_t)l * NGR * D);
        gather_kernel<<<gather_blocks, 256, 0, stream>>>(h, z, rowptr, col, N);
        // GEMM1: z -> h
        gemm_kernel<false><<<gemm_grid, 256, 0, stream>>>(
            z, W1 + (size_t)l * D * D, b1 + l * D, sc1, h, N);
        hipMemsetAsync(stats, 0, 2 * D * sizeof(float), stream);
        colstats_kernel<<<128, 320, 0, stream>>>(h, stats, N);
        bnfin_kernel<<<1, 320, 0, stream>>>(stats, g1 + l * D, be1 + l * D, sc1, invN);
        // GEMM2 (BN1+ReLU fused on A-load): h -> z
        gemm_kernel<true><<<gemm_grid, 256, 0, stream>>>(
            h, W2 + (size_t)l * D * D, b2 + l * D, sc1, z, N);
        hipMemsetAsync(stats, 0, 2 * D * sizeof(float), stream);
        colstats_kernel<<<128, 320, 0, stream>>>(z, stats, N);
        bnfin_kernel<<<1, 320, 0, stream>>>(stats, bng + l * D, bnb + l * D, sc2, invN);
        // BN2+ReLU: z -> h
        bnapply_kernel<<<bnapply_blocks, 256, 0, stream>>>(z, h, sc2, n4);
    }
    pool_kernel<<<dim3(NGR, 4), 320, 0, stream>>>(h, off, pooled + (size_t)NL * NGR * D);
    readout_kernel<<<NGR / 8, 128, 0, stream>>>(pooled, off, fcW, fcb, out);
}

// Round 4
// 3423.910 us; speedup vs baseline: 3.3795x; 1.0476x over previous
//
#include <hip/hip_runtime.h>

#define D 300
#define KPAD 320
#define NGR 256
#define NL 5
#define NC 128
#define BN_EPS 1e-5f

typedef __attribute__((ext_vector_type(8))) short bf16x8;
typedef __attribute__((ext_vector_type(4))) float f32x4;

__device__ __forceinline__ void atomAdd(float* p, float v) { unsafeAtomicAdd(p, v); }

__device__ __forceinline__ short f2bf(float f) {
    union { float f; unsigned u; } v; v.f = f;
    unsigned r = v.u + 0x7fffu + ((v.u >> 16) & 1u);   // RNE
    return (short)(r >> 16);
}

// ---------------------------------------------------------------------------
// offsets: off[g] = lower_bound(batch, g)
// ---------------------------------------------------------------------------
__global__ void offsets_kernel(const int* __restrict__ batch, int* __restrict__ off, int N) {
    int g = threadIdx.x;
    if (g > NGR) return;
    int lo = 0, hi = N;
    while (lo < hi) {
        int mid = (lo + hi) >> 1;
        if (batch[mid] < g) lo = mid + 1; else hi = mid;
    }
    off[g] = lo;
}

// ---------------------------------------------------------------------------
// CSR build
// ---------------------------------------------------------------------------
__global__ __launch_bounds__(256)
void deg_kernel(const int* __restrict__ ei, int* __restrict__ deg, int E) {
    int e = blockIdx.x * 256 + threadIdx.x;
    if (e < E) atomicAdd(&deg[ei[E + e]], 1);
}

__global__ __launch_bounds__(1024)
void scan_kernel(const int* __restrict__ deg, int* __restrict__ rowptr, int N) {
    __shared__ int part[1024];
    int t = threadIdx.x;
    int per = (N + 1023) / 1024;
    int a = t * per, b = min(a + per, N);
    int s = 0;
    for (int i = a; i < b; ++i) s += deg[i];
    part[t] = s;
    __syncthreads();
    for (int off = 1; off < 1024; off <<= 1) {
        int v = (t >= off) ? part[t - off] : 0;
        __syncthreads();
        part[t] += v;
        __syncthreads();
    }
    int base = (t == 0) ? 0 : part[t - 1];
    for (int i = a; i < b; ++i) { rowptr[i] = base; base += deg[i]; }
    if (t == 1023) rowptr[N] = base;
}

__global__ __launch_bounds__(256)
void fill_kernel(const int* __restrict__ ei, const int* __restrict__ rowptr,
                 int* __restrict__ cursor, int* __restrict__ col, int E) {
    int e = blockIdx.x * 256 + threadIdx.x;
    if (e >= E) return;
    int src = ei[e];
    int dst = ei[E + e];
    int pos = atomicAdd(&cursor[dst], 1);
    col[rowptr[dst] + pos] = src;
}

// ---------------------------------------------------------------------------
// gather: Z[i] = H[i] + sum_{j in N(i)} H[j]
// ---------------------------------------------------------------------------
__global__ __launch_bounds__(256)
void gather_kernel(const float* __restrict__ H, float* __restrict__ Z,
                   const int* __restrict__ rowptr, const int* __restrict__ col, int N) {
    int idx = blockIdx.x * 256 + threadIdx.x;
    if (idx >= N * 75) return;
    int node = idx / 75;
    int c = (idx - node * 75) * 4;
    int s = rowptr[node], e = rowptr[node + 1];
    float4 acc = *(const float4*)(H + (size_t)node * D + c);
    for (int j = s; j < e; ++j) {
        int src = col[j];
        const float4 v = *(const float4*)(H + (size_t)src * D + c);
        acc.x += v.x; acc.y += v.y; acc.z += v.z; acc.w += v.w;
    }
    *(float4*)(Z + (size_t)node * D + c) = acc;
}

// ---------------------------------------------------------------------------
// pool
// ---------------------------------------------------------------------------
__global__ __launch_bounds__(320)
void pool_kernel(const float* __restrict__ H, const int* __restrict__ off,
                 float* __restrict__ pooled_l) {
    int c = threadIdx.x;
    if (c >= D) return;
    int g = blockIdx.x;
    int chunk = blockIdx.y;
    int r0 = off[g], r1 = off[g + 1];
    int len = r1 - r0;
    int per = (len + 3) >> 2;
    int a = r0 + chunk * per;
    int b = min(a + per, r1);
    float s = 0.f;
    for (int r = a; r < b; ++r) s += H[r * D + c];
    if (b > a) atomAdd(&pooled_l[g * D + c], s);
}

// ---------------------------------------------------------------------------
// MFMA GEMM: C = op(A) @ W + bias, bf16 inputs, fp32 accum.
// Block: 128 rows x 64 cols, 256 threads (4 waves), K padded to 320.
// W^T slab staged once (bf16, transposed); A chunks (32 k) staged per iter.
// APPLY: op(a)[m][k] = relu(a*scsh[k] + scsh[D+k]) fused into A staging.
// ---------------------------------------------------------------------------
template<bool APPLY>
__global__ __launch_bounds__(256)
void mfma_gemm_kernel(const float* __restrict__ A, const float* __restrict__ W,
                      const float* __restrict__ bias, const float* __restrict__ scsh,
                      float* __restrict__ Cmat, int M) {
    __shared__ short Ws[64][328];   // [n][k] bf16; 656B rows: 16B-aligned, 2-way banks (free)
    __shared__ short As[128][40];   // [m][k] bf16; 80B rows: 16B-aligned, 2-way banks (free)

    const int tid = threadIdx.x;
    const int m0 = blockIdx.x * 128;
    const int n0 = blockIdx.y * 64;

    // ---- stage W^T slab: Ws[n][k] = bf16(W[k][n0+n]); zero pad k>=D / col>=D
    {
        int n4 = (tid & 15) * 4;
        int kbase = tid >> 4;
        bool colok = (n0 + n4 + 3) < D;
        for (int p = 0; p < 20; ++p) {
            int k = p * 16 + kbase;
            float4 w = make_float4(0.f, 0.f, 0.f, 0.f);
            if (k < D && colok) w = *(const float4*)(W + (size_t)k * D + n0 + n4);
            Ws[n4 + 0][k] = f2bf(w.x);
            Ws[n4 + 1][k] = f2bf(w.y);
            Ws[n4 + 2][k] = f2bf(w.z);
            Ws[n4 + 3][k] = f2bf(w.w);
        }
    }

    const int wave = tid >> 6;
    const int lane = tid & 63;
    const int quad = lane >> 4;
    const int l16  = lane & 15;
    const int tm0  = wave * 32;

    f32x4 acc[2][4] = {};

    for (int kc = 0; kc < KPAD; kc += 32) {
        __syncthreads();   // protects Ws (iter 0) and As reuse
        // ---- stage A chunk
        {
            int r = tid >> 1;
            int kt = (tid & 1) * 16;
            int m = m0 + r;
            float vbuf[16];
            #pragma unroll
            for (int o = 0; o < 4; ++o) {
                int kk = kc + kt + o * 4;
                float4 v = make_float4(0.f, 0.f, 0.f, 0.f);
                if (m < M && kk + 3 < D) v = *(const float4*)(A + (size_t)m * D + kk);
                vbuf[o * 4 + 0] = v.x; vbuf[o * 4 + 1] = v.y;
                vbuf[o * 4 + 2] = v.z; vbuf[o * 4 + 3] = v.w;
            }
            if (APPLY) {
                #pragma unroll
                for (int i = 0; i < 16; ++i) {
                    int kk = kc + kt + i;
                    if (kk < D)   // keep zero-pad zero (relu(sh) != 0 otherwise)
                        vbuf[i] = fmaxf(fmaf(vbuf[i], scsh[kk], scsh[D + kk]), 0.f);
                }
            }
            #pragma unroll
            for (int o = 0; o < 4; ++o) {
                short4 s4 = make_short4(f2bf(vbuf[o * 4 + 0]), f2bf(vbuf[o * 4 + 1]),
                                        f2bf(vbuf[o * 4 + 2]), f2bf(vbuf[o * 4 + 3]));
                *(short4*)&As[r][kt + o * 4] = s4;
            }
        }
        __syncthreads();

        // ---- compute: 4 b-frags, 2 a-frags, 8 MFMAs
        bf16x8 b[4];
        #pragma unroll
        for (int nt = 0; nt < 4; ++nt)
            b[nt] = *(const bf16x8*)&Ws[nt * 16 + l16][kc + quad * 8];
        #pragma unroll
        for (int t = 0; t < 2; ++t) {
            bf16x8 a = *(const bf16x8*)&As[tm0 + t * 16 + l16][quad * 8];
            #pragma unroll
            for (int nt = 0; nt < 4; ++nt)
                acc[t][nt] = __builtin_amdgcn_mfma_f32_16x16x32_bf16(a, b[nt], acc[t][nt], 0, 0, 0);
        }
    }

    // ---- epilogue: C[row=quad*4+reg][col=l16] per tile
    #pragma unroll
    for (int nt = 0; nt < 4; ++nt) {
        int colg = n0 + nt * 16 + l16;
        if (colg >= D) continue;
        float bia = bias[colg];
        #pragma unroll
        for (int t = 0; t < 2; ++t) {
            #pragma unroll
            for (int r = 0; r < 4; ++r) {
                int m = m0 + tm0 + t * 16 + quad * 4 + r;
                if (m < M) Cmat[(size_t)m * D + colg] = acc[t][nt][r] + bia;
            }
        }
    }
}

// ---------------------------------------------------------------------------
// column stats
// ---------------------------------------------------------------------------
__global__ __launch_bounds__(320)
void colstats_kernel(const float* __restrict__ T, float* __restrict__ sums, int M) {
    int c = threadIdx.x;
    if (c >= D) return;
    int nb = gridDim.x;
    int per = (M + nb - 1) / nb;
    int r0 = blockIdx.x * per;
    int r1 = min(r0 + per, M);
    float s = 0.f, ss = 0.f;
    for (int r = r0; r < r1; ++r) {
        float v = T[r * D + c];
        s += v;
        ss = fmaf(v, v, ss);
    }
    atomAdd(&sums[c], s);
    atomAdd(&sums[D + c], ss);
}

__global__ void bnfin_kernel(const float* __restrict__ sums, const float* __restrict__ g,
                             const float* __restrict__ be, float* __restrict__ scsh, float invN) {
    int c = threadIdx.x;
    if (c >= D) return;
    float mu = sums[c] * invN;
    float var = sums[D + c] * invN - mu * mu;
    float s = g[c] / sqrtf(var + BN_EPS);
    scsh[c] = s;
    scsh[D + c] = fmaf(-mu, s, be[c]);
}

__global__ __launch_bounds__(256)
void bnapply_kernel(const float* __restrict__ Z, float* __restrict__ H,
                    const float* __restrict__ scsh, int n4) {
    int i = blockIdx.x * 256 + threadIdx.x;
    if (i >= n4) return;
    int base = i * 4;
    int c = base % D;
    float4 v = *(const float4*)(Z + base);
    v.x = fmaxf(fmaf(v.x, scsh[c],     scsh[D + c]),     0.f);
    v.y = fmaxf(fmaf(v.y, scsh[c + 1], scsh[D + c + 1]), 0.f);
    v.z = fmaxf(fmaf(v.z, scsh[c + 2], scsh[D + c + 2]), 0.f);
    v.w = fmaxf(fmaf(v.w, scsh[c + 3], scsh[D + c + 3]), 0.f);
    *(float4*)(H + base) = v;
}

// ---------------------------------------------------------------------------
// readout: out pre-init with summed biases; per-(4-graphs, layer) blocks atomAdd
// ---------------------------------------------------------------------------
__global__ __launch_bounds__(128)
void bias_init_kernel(const float* __restrict__ fcb, float* __restrict__ out) {
    int i = blockIdx.x * 128 + threadIdx.x;
    if (i >= NGR * NC) return;
    int c = i & (NC - 1);
    float s = 0.f;
    for (int l = 0; l <= NL; ++l) s += fcb[l * NC + c];
    out[i] = s;
}

__global__ __launch_bounds__(128)
void readout_kernel(const float* __restrict__ pooled, const int* __restrict__ off,
                    const float* __restrict__ fcW, float* __restrict__ out) {
    __shared__ float sp[4][D];
    int c = threadIdx.x;
    int l = blockIdx.y;
    int g0 = blockIdx.x * 4;
    for (int i = c; i < 4 * D; i += 128) {
        int gg = i / D, k = i - gg * D;
        sp[gg][k] = pooled[((size_t)l * NGR + g0 + gg) * D + k];
    }
    __syncthreads();
    float acc[4] = {0.f, 0.f, 0.f, 0.f};
    for (int k = 0; k < D; ++k) {
        float w = fcW[((size_t)l * D + k) * NC + c];
        #pragma unroll
        for (int gg = 0; gg < 4; ++gg) acc[gg] = fmaf(sp[gg][k], w, acc[gg]);
    }
    #pragma unroll
    for (int gg = 0; gg < 4; ++gg) {
        int g = g0 + gg;
        float inv = 1.0f / fmaxf((float)(off[g + 1] - off[g]), 1.0f);
        atomAdd(&out[g * NC + c], acc[gg] * inv);
    }
}

// ---------------------------------------------------------------------------
extern "C" void kernel_launch(void* const* d_in, const int* in_sizes, int n_in,
                              void* d_out, int out_size, void* d_ws, size_t ws_size,
                              hipStream_t stream) {
    const float* x       = (const float*)d_in[0];
    const int*   ei      = (const int*)d_in[1];
    const int*   batch   = (const int*)d_in[2];
    const float* W1  = (const float*)d_in[3];
    const float* b1  = (const float*)d_in[4];
    const float* g1  = (const float*)d_in[5];
    const float* be1 = (const float*)d_in[6];
    const float* W2  = (const float*)d_in[7];
    const float* b2  = (const float*)d_in[8];
    const float* bng = (const float*)d_in[9];
    const float* bnb = (const float*)d_in[10];
    const float* fcW = (const float*)d_in[11];
    const float* fcb = (const float*)d_in[12];
    float* out = (float*)d_out;

    const int N = in_sizes[0] / D;   // 50000
    const int E = in_sizes[1] / 2;   // 400000
    const size_t ND = (size_t)N * D;

    float* h      = (float*)d_ws;
    float* z      = h + ND;
    float* pooled = z + ND;                                  // (NL+1)*NGR*D
    float* stats  = pooled + (size_t)(NL + 1) * NGR * D;     // 2*D
    float* sc1    = stats + 2 * D;                           // 2*D
    float* sc2    = sc1 + 2 * D;                             // 2*D
    int*   off    = (int*)(sc2 + 2 * D);                     // NGR+1
    int*   rowptr = off + NGR + 1;                           // N+1
    int*   cursor = rowptr + N + 1;                          // N
    int*   col    = cursor + N;                              // E

    hipMemcpyAsync(h, x, ND * sizeof(float), hipMemcpyDeviceToDevice, stream);
    hipMemsetAsync(pooled, 0, (size_t)(NL + 1) * NGR * D * sizeof(float), stream);
    offsets_kernel<<<1, 320, 0, stream>>>(batch, off, N);
    bias_init_kernel<<<(NGR * NC + 127) / 128, 128, 0, stream>>>(fcb, out);

    // ---- CSR build (once) ----
    hipMemsetAsync(cursor, 0, N * sizeof(int), stream);
    deg_kernel<<<(E + 255) / 256, 256, 0, stream>>>(ei, cursor, E);
    scan_kernel<<<1, 1024, 0, stream>>>(cursor, rowptr, N);
    hipMemsetAsync(cursor, 0, N * sizeof(int), stream);
    fill_kernel<<<(E + 255) / 256, 256, 0, stream>>>(ei, rowptr, cursor, col, E);

    dim3 gemm_grid((N + 127) / 128, 5);
    int gather_blocks = (N * 75 + 255) / 256;
    int n4 = (int)(ND / 4);
    int bnapply_blocks = (n4 + 255) / 256;
    float invN = 1.0f / (float)N;

    for (int l = 0; l < NL; ++l) {
        pool_kernel<<<dim3(NGR, 4), 320, 0, stream>>>(h, off, pooled + (size_t)l * NGR * D);
        gather_kernel<<<gather_blocks, 256, 0, stream>>>(h, z, rowptr, col, N);
        mfma_gemm_kernel<false><<<gemm_grid, 256, 0, stream>>>(
            z, W1 + (size_t)l * D * D, b1 + l * D, sc1, h, N);
        hipMemsetAsync(stats, 0, 2 * D * sizeof(float), stream);
        colstats_kernel<<<128, 320, 0, stream>>>(h, stats, N);
        bnfin_kernel<<<1, 320, 0, stream>>>(stats, g1 + l * D, be1 + l * D, sc1, invN);
        mfma_gemm_kernel<true><<<gemm_grid, 256, 0, stream>>>(
            h, W2 + (size_t)l * D * D, b2 + l * D, sc1, z, N);
        hipMemsetAsync(stats, 0, 2 * D * sizeof(float), stream);
        colstats_kernel<<<128, 320, 0, stream>>>(z, stats, N);
        bnfin_kernel<<<1, 320, 0, stream>>>(stats, bng + l * D, bnb + l * D, sc2, invN);
        bnapply_kernel<<<bnapply_blocks, 256, 0, stream>>>(z, h, sc2, n4);
    }
    pool_kernel<<<dim3(NGR, 4), 320, 0, stream>>>(h, off, pooled + (size_t)NL * NGR * D);
    readout_kernel<<<dim3(NGR / 4, NL + 1), 128, 0, stream>>>(pooled, off, fcW, out);
}

// Round 5
// 2778.199 us; speedup vs baseline: 4.1649x; 1.2324x over previous
//
#include <hip/hip_runtime.h>

#define D 300
#define KP 320
#define NPAD 50048
#define NGR 256
#define NL 5
#define NC 128
#define BN_EPS 1e-5f

typedef __attribute__((ext_vector_type(8))) short bf16x8;
typedef __attribute__((ext_vector_type(4))) float f32x4;
typedef unsigned short u16;

__device__ __forceinline__ void atomAdd(float* p, float v) { unsafeAtomicAdd(p, v); }

__device__ __forceinline__ short f2bf(float f) {
    union { float f; unsigned u; } v; v.f = f;
    unsigned r = v.u + 0x7fffu + ((v.u >> 16) & 1u);   // RNE
    return (short)(r >> 16);
}
__device__ __forceinline__ float bf2f(short s) {
    union { unsigned u; float f; } v;
    v.u = ((unsigned)(u16)s) << 16;
    return v.f;
}

// ---------------------------------------------------------------------------
// offsets: off[g] = lower_bound(batch, g)
// ---------------------------------------------------------------------------
__global__ void offsets_kernel(const int* __restrict__ batch, int* __restrict__ off, int N) {
    int g = threadIdx.x;
    if (g > NGR) return;
    int lo = 0, hi = N;
    while (lo < hi) {
        int mid = (lo + hi) >> 1;
        if (batch[mid] < g) lo = mid + 1; else hi = mid;
    }
    off[g] = lo;
}

// ---------------------------------------------------------------------------
// CSR build
// ---------------------------------------------------------------------------
__global__ __launch_bounds__(256)
void deg_kernel(const int* __restrict__ ei, int* __restrict__ deg, int E) {
    int e = blockIdx.x * 256 + threadIdx.x;
    if (e < E) atomicAdd(&deg[ei[E + e]], 1);
}

__global__ __launch_bounds__(1024)
void scan_kernel(const int* __restrict__ deg, int* __restrict__ rowptr, int N) {
    __shared__ int part[1024];
    int t = threadIdx.x;
    int per = (N + 1023) / 1024;
    int a = t * per, b = min(a + per, N);
    int s = 0;
    for (int i = a; i < b; ++i) s += deg[i];
    part[t] = s;
    __syncthreads();
    for (int off = 1; off < 1024; off <<= 1) {
        int v = (t >= off) ? part[t - off] : 0;
        __syncthreads();
        part[t] += v;
        __syncthreads();
    }
    int base = (t == 0) ? 0 : part[t - 1];
    for (int i = a; i < b; ++i) { rowptr[i] = base; base += deg[i]; }
    if (t == 1023) rowptr[N] = base;
}

__global__ __launch_bounds__(256)
void fill_kernel(const int* __restrict__ ei, const int* __restrict__ rowptr,
                 int* __restrict__ cursor, int* __restrict__ col, int E) {
    int e = blockIdx.x * 256 + threadIdx.x;
    if (e >= E) return;
    int src = ei[e];
    int dst = ei[E + e];
    int pos = atomicAdd(&cursor[dst], 1);
    col[rowptr[dst] + pos] = src;
}

// ---------------------------------------------------------------------------
// weight convert: Wt[mat][n (304)][k (320)] = bf16(W[k][n]); pads zero
// ---------------------------------------------------------------------------
__global__ __launch_bounds__(256)
void wcvt_kernel(const float* __restrict__ W1, const float* __restrict__ W2,
                 u16* __restrict__ Wt) {
    int idx = blockIdx.x * 256 + threadIdx.x;
    if (idx >= 10 * KP * 76) return;
    int n4 = idx % 76;
    int k = (idx / 76) % KP;
    int mat = idx / (76 * KP);
    const float* Wsrc = (mat < NL) ? (W1 + (size_t)mat * D * D) : (W2 + (size_t)(mat - NL) * D * D);
    float4 w = make_float4(0.f, 0.f, 0.f, 0.f);
    if (k < D && n4 < 75) w = *(const float4*)(Wsrc + (size_t)k * D + n4 * 4);
    size_t base = ((size_t)mat * 304 + n4 * 4) * KP + k;
    Wt[base]          = (u16)f2bf(w.x);
    Wt[base + KP]     = (u16)f2bf(w.y);
    Wt[base + 2 * KP] = (u16)f2bf(w.z);
    Wt[base + 3 * KP] = (u16)f2bf(w.w);
}

// ---------------------------------------------------------------------------
// x convert: hbf[row][c] = bf16(x[row][c]), pads (c>=300, row>=N) zero
// ---------------------------------------------------------------------------
__global__ __launch_bounds__(256)
void xcvt_kernel(const float* __restrict__ x, u16* __restrict__ hbf, int N) {
    int idx = blockIdx.x * 256 + threadIdx.x;
    if (idx >= NPAD * 40) return;
    int row = idx / 40;
    int c8 = (idx - row * 40) * 8;
    short o[8];
    #pragma unroll
    for (int i = 0; i < 8; ++i) {
        int c = c8 + i;
        float f = (row < N && c < D) ? x[(size_t)row * D + c] : 0.f;
        o[i] = f2bf(f);
    }
    *(bf16x8*)(hbf + (size_t)row * KP + c8) = *(bf16x8*)o;
}

// ---------------------------------------------------------------------------
// gather: zbf[i] = bf16( hbf[i] + sum_{j in N(i)} hbf[j] )  (fp32 accum)
// thread = (node, 8-col group)
// ---------------------------------------------------------------------------
__global__ __launch_bounds__(256)
void gather_kernel(const u16* __restrict__ H, u16* __restrict__ Z,
                   const int* __restrict__ rowptr, const int* __restrict__ col, int N) {
    int idx = blockIdx.x * 256 + threadIdx.x;
    if (idx >= N * 40) return;
    int node = idx / 40;
    int c8 = (idx - node * 40) * 8;
    int s = rowptr[node], e = rowptr[node + 1];
    bf16x8 v = *(const bf16x8*)(H + (size_t)node * KP + c8);
    float acc[8];
    #pragma unroll
    for (int i = 0; i < 8; ++i) acc[i] = bf2f(v[i]);
    for (int j = s; j < e; ++j) {
        int src = col[j];
        bf16x8 w = *(const bf16x8*)(H + (size_t)src * KP + c8);
        #pragma unroll
        for (int i = 0; i < 8; ++i) acc[i] += bf2f(w[i]);
    }
    short o[8];
    #pragma unroll
    for (int i = 0; i < 8; ++i) o[i] = f2bf(acc[i]);
    *(bf16x8*)(Z + (size_t)node * KP + c8) = *(bf16x8*)o;
}

// ---------------------------------------------------------------------------
// pool (bf16 input, fp32 accumulate)
// ---------------------------------------------------------------------------
__global__ __launch_bounds__(320)
void pool_kernel(const u16* __restrict__ H, const int* __restrict__ off,
                 float* __restrict__ pooled_l) {
    int c = threadIdx.x;
    if (c >= D) return;
    int g = blockIdx.x;
    int chunk = blockIdx.y;
    int r0 = off[g], r1 = off[g + 1];
    int len = r1 - r0;
    int per = (len + 3) >> 2;
    int a = r0 + chunk * per;
    int b = min(a + per, r1);
    float s = 0.f;
    for (int r = a; r < b; ++r) s += bf2f(H[(size_t)r * KP + c]);
    if (b > a) atomAdd(&pooled_l[g * D + c], s);
}

// ---------------------------------------------------------------------------
// MFMA GEMM, barrier-free, no LDS.
// C = op(A) @ W + bias; A bf16 [NPAD][KP], Wt bf16 [304 n][KP k], C bf16.
// Block = 4 waves; wave owns 16 rows x 304 cols (19 n-tiles, acc[19] f32x4).
// a/b frags are direct global bf16x8 loads in MFMA lane layout:
//   A[m=l16][k=quad*8+j], B[n=l16][k=quad*8+j]; wave load = 16 rows x 64B.
// APPLY: a := relu(a*scale[k]+shift[k]) on the fly (pads: scale=shift=0).
// ---------------------------------------------------------------------------
template<bool APPLY>
__global__ __launch_bounds__(256)
void mfma_gemm_kernel(const u16* __restrict__ Abf, const u16* __restrict__ Wt,
                      const float* __restrict__ bias, const float* __restrict__ scsh,
                      u16* __restrict__ Cbf) {
    const int tid = threadIdx.x;
    const int wave = tid >> 6, lane = tid & 63;
    const int quad = lane >> 4, l16 = lane & 15;
    const int mBase = blockIdx.x * 64 + wave * 16;

    const u16* arow = Abf + (size_t)(mBase + l16) * KP + quad * 8;
    const u16* wrow = Wt + (size_t)l16 * KP + quad * 8;

    f32x4 acc[19] = {};

    for (int kc = 0; kc < KP; kc += 32) {
        bf16x8 a = *(const bf16x8*)(arow + kc);
        if (APPLY) {
            const float* sp = scsh + kc + quad * 8;
            float4 s0 = *(const float4*)sp;
            float4 s1 = *(const float4*)(sp + 4);
            float4 h0 = *(const float4*)(sp + KP);
            float4 h1 = *(const float4*)(sp + KP + 4);
            float sc[8] = {s0.x, s0.y, s0.z, s0.w, s1.x, s1.y, s1.z, s1.w};
            float sh[8] = {h0.x, h0.y, h0.z, h0.w, h1.x, h1.y, h1.z, h1.w};
            short o[8];
            #pragma unroll
            for (int i = 0; i < 8; ++i)
                o[i] = f2bf(fmaxf(fmaf(bf2f(a[i]), sc[i], sh[i]), 0.f));
            a = *(bf16x8*)o;
        }
        #pragma unroll
        for (int nt = 0; nt < 19; ++nt) {
            bf16x8 b = *(const bf16x8*)(wrow + (size_t)nt * 16 * KP + kc);
            acc[nt] = __builtin_amdgcn_mfma_f32_16x16x32_bf16(a, b, acc[nt], 0, 0, 0);
        }
    }

    // epilogue: C[row = mBase + quad*4 + r][col = nt*16 + l16]
    const int rbase = mBase + quad * 4;
    #pragma unroll
    for (int nt = 0; nt < 19; ++nt) {
        int colg = nt * 16 + l16;
        if (colg >= D) continue;   // only nt=18, l16>=12
        float bia = bias[colg];
        #pragma unroll
        for (int r = 0; r < 4; ++r)
            Cbf[(size_t)(rbase + r) * KP + colg] = (u16)f2bf(acc[nt][r] + bia);
    }
}

// ---------------------------------------------------------------------------
// column stats from bf16: stats[c] += sum, stats[KP+c] += sumsq
// ---------------------------------------------------------------------------
__global__ __launch_bounds__(320)
void colstats_kernel(const u16* __restrict__ T, float* __restrict__ sums, int M) {
    int c = threadIdx.x;
    if (c >= D) return;
    int nb = gridDim.x;
    int per = (M + nb - 1) / nb;
    int r0 = blockIdx.x * per;
    int r1 = min(r0 + per, M);
    float s = 0.f, ss = 0.f;
    for (int r = r0; r < r1; ++r) {
        float v = bf2f(T[(size_t)r * KP + c]);
        s += v;
        ss = fmaf(v, v, ss);
    }
    atomAdd(&sums[c], s);
    atomAdd(&sums[KP + c], ss);
}

__global__ void bnfin_kernel(const float* __restrict__ sums, const float* __restrict__ g,
                             const float* __restrict__ be, float* __restrict__ scsh, float invN) {
    int c = threadIdx.x;
    if (c >= D) return;
    float mu = sums[c] * invN;
    float var = sums[KP + c] * invN - mu * mu;
    float s = g[c] / sqrtf(var + BN_EPS);
    scsh[c] = s;
    scsh[KP + c] = fmaf(-mu, s, be[c]);
}

// ---------------------------------------------------------------------------
// BN2 apply + ReLU: hbf = bf16(relu(zbf*scale+shift)); pads stay 0 (sc pads 0)
// ---------------------------------------------------------------------------
__global__ __launch_bounds__(256)
void bnapply_kernel(const u16* __restrict__ Z, u16* __restrict__ H,
                    const float* __restrict__ scsh, int N) {
    int idx = blockIdx.x * 256 + threadIdx.x;
    if (idx >= N * 40) return;
    int row = idx / 40;
    int c8 = (idx - row * 40) * 8;
    bf16x8 v = *(const bf16x8*)(Z + (size_t)row * KP + c8);
    const float* sp = scsh + c8;
    float4 s0 = *(const float4*)sp;
    float4 s1 = *(const float4*)(sp + 4);
    float4 h0 = *(const float4*)(sp + KP);
    float4 h1 = *(const float4*)(sp + KP + 4);
    float sc[8] = {s0.x, s0.y, s0.z, s0.w, s1.x, s1.y, s1.z, s1.w};
    float sh[8] = {h0.x, h0.y, h0.z, h0.w, h1.x, h1.y, h1.z, h1.w};
    short o[8];
    #pragma unroll
    for (int i = 0; i < 8; ++i)
        o[i] = f2bf(fmaxf(fmaf(bf2f(v[i]), sc[i], sh[i]), 0.f));
    *(bf16x8*)(H + (size_t)row * KP + c8) = *(bf16x8*)o;
}

// ---------------------------------------------------------------------------
// readout
// ---------------------------------------------------------------------------
__global__ __launch_bounds__(128)
void bias_init_kernel(const float* __restrict__ fcb, float* __restrict__ out) {
    int i = blockIdx.x * 128 + threadIdx.x;
    if (i >= NGR * NC) return;
    int c = i & (NC - 1);
    float s = 0.f;
    for (int l = 0; l <= NL; ++l) s += fcb[l * NC + c];
    out[i] = s;
}

__global__ __launch_bounds__(128)
void readout_kernel(const float* __restrict__ pooled, const int* __restrict__ off,
                    const float* __restrict__ fcW, float* __restrict__ out) {
    __shared__ float sp[4][D];
    int c = threadIdx.x;
    int l = blockIdx.y;
    int g0 = blockIdx.x * 4;
    for (int i = c; i < 4 * D; i += 128) {
        int gg = i / D, k = i - gg * D;
        sp[gg][k] = pooled[((size_t)l * NGR + g0 + gg) * D + k];
    }
    __syncthreads();
    float acc[4] = {0.f, 0.f, 0.f, 0.f};
    for (int k = 0; k < D; ++k) {
        float w = fcW[((size_t)l * D + k) * NC + c];
        #pragma unroll
        for (int gg = 0; gg < 4; ++gg) acc[gg] = fmaf(sp[gg][k], w, acc[gg]);
    }
    #pragma unroll
    for (int gg = 0; gg < 4; ++gg) {
        int g = g0 + gg;
        float inv = 1.0f / fmaxf((float)(off[g + 1] - off[g]), 1.0f);
        atomAdd(&out[g * NC + c], acc[gg] * inv);
    }
}

// ---------------------------------------------------------------------------
extern "C" void kernel_launch(void* const* d_in, const int* in_sizes, int n_in,
                              void* d_out, int out_size, void* d_ws, size_t ws_size,
                              hipStream_t stream) {
    const float* x       = (const float*)d_in[0];
    const int*   ei      = (const int*)d_in[1];
    const int*   batch   = (const int*)d_in[2];
    const float* W1  = (const float*)d_in[3];
    const float* b1  = (const float*)d_in[4];
    const float* g1  = (const float*)d_in[5];
    const float* be1 = (const float*)d_in[6];
    const float* W2  = (const float*)d_in[7];
    const float* b2  = (const float*)d_in[8];
    const float* bng = (const float*)d_in[9];
    const float* bnb = (const float*)d_in[10];
    const float* fcW = (const float*)d_in[11];
    const float* fcb = (const float*)d_in[12];
    float* out = (float*)d_out;

    const int N = in_sizes[0] / D;   // 50000
    const int E = in_sizes[1] / 2;   // 400000

    // ---- workspace layout (16B-aligned bf16 buffers first) ----
    u16* hbf = (u16*)d_ws;                       // NPAD*KP
    u16* zbf = hbf + (size_t)NPAD * KP;          // NPAD*KP
    u16* Wt  = zbf + (size_t)NPAD * KP;          // 10*304*KP
    float* pooled = (float*)(Wt + (size_t)10 * 304 * KP);    // 6*NGR*D
    float* stats  = pooled + (size_t)(NL + 1) * NGR * D;     // 2*KP
    float* sc1    = stats + 2 * KP;                          // 2*KP
    float* sc2    = sc1 + 2 * KP;                            // 2*KP
    int*   off    = (int*)(sc2 + 2 * KP);                    // NGR+1
    int*   rowptr = off + NGR + 1;                           // N+1
    int*   cursor = rowptr + N + 1;                          // N
    int*   col    = cursor + N;                              // E

    hipMemsetAsync(pooled, 0, (size_t)(NL + 1) * NGR * D * sizeof(float), stream);
    hipMemsetAsync(stats, 0, 6 * KP * sizeof(float), stream);   // stats + sc1 + sc2 (pads!)
    offsets_kernel<<<1, 320, 0, stream>>>(batch, off, N);
    bias_init_kernel<<<(NGR * NC + 127) / 128, 128, 0, stream>>>(fcb, out);

    // ---- CSR build (once) ----
    hipMemsetAsync(cursor, 0, N * sizeof(int), stream);
    deg_kernel<<<(E + 255) / 256, 256, 0, stream>>>(ei, cursor, E);
    scan_kernel<<<1, 1024, 0, stream>>>(cursor, rowptr, N);
    hipMemsetAsync(cursor, 0, N * sizeof(int), stream);
    fill_kernel<<<(E + 255) / 256, 256, 0, stream>>>(ei, rowptr, cursor, col, E);

    // ---- precompute bf16 weights + input ----
    wcvt_kernel<<<(10 * KP * 76 + 255) / 256, 256, 0, stream>>>(W1, W2, Wt);
    xcvt_kernel<<<(NPAD * 40 + 255) / 256, 256, 0, stream>>>(x, hbf, N);

    const int gemm_blocks = NPAD / 64;           // 782
    const int nd40 = N * 40;
    float invN = 1.0f / (float)N;
    const size_t WtM = (size_t)304 * KP;

    for (int l = 0; l < NL; ++l) {
        pool_kernel<<<dim3(NGR, 4), 320, 0, stream>>>(hbf, off, pooled + (size_t)l * NGR * D);
        gather_kernel<<<(nd40 + 255) / 256, 256, 0, stream>>>(hbf, zbf, rowptr, col, N);
        // GEMM1: zbf @ W1 -> hbf
        mfma_gemm_kernel<false><<<gemm_blocks, 256, 0, stream>>>(
            zbf, Wt + (size_t)l * WtM, b1 + l * D, sc1, hbf);
        hipMemsetAsync(stats, 0, 2 * KP * sizeof(float), stream);
        colstats_kernel<<<128, 320, 0, stream>>>(hbf, stats, N);
        bnfin_kernel<<<1, 320, 0, stream>>>(stats, g1 + l * D, be1 + l * D, sc1, invN);
        // GEMM2 (BN1+ReLU on the fly): hbf @ W2 -> zbf
        mfma_gemm_kernel<true><<<gemm_blocks, 256, 0, stream>>>(
            hbf, Wt + (size_t)(NL + l) * WtM, b2 + l * D, sc1, zbf);
        hipMemsetAsync(stats, 0, 2 * KP * sizeof(float), stream);
        colstats_kernel<<<128, 320, 0, stream>>>(zbf, stats, N);
        bnfin_kernel<<<1, 320, 0, stream>>>(stats, bng + l * D, bnb + l * D, sc2, invN);
        // BN2+ReLU: zbf -> hbf
        bnapply_kernel<<<(nd40 + 255) / 256, 256, 0, stream>>>(zbf, hbf, sc2, N);
    }
    pool_kernel<<<dim3(NGR, 4), 320, 0, stream>>>(hbf, off, pooled + (size_t)NL * NGR * D);
    readout_kernel<<<dim3(NGR / 4, NL + 1), 128, 0, stream>>>(pooled, off, fcW, out);
}

// Round 7
// 1866.669 us; speedup vs baseline: 6.1988x; 1.4883x over previous
//
#include <hip/hip_runtime.h>

#define D 300
#define KP 320
#define NPAD 50048
#define NGR 256
#define NL 5
#define NC 128
#define BN_EPS 1e-5f

typedef __attribute__((ext_vector_type(8))) short bf16x8;
typedef __attribute__((ext_vector_type(4))) float f32x4;
typedef unsigned short u16;

__device__ __forceinline__ void atomAdd(float* p, float v) { unsafeAtomicAdd(p, v); }

__device__ __forceinline__ short f2bf(float f) {
    union { float f; unsigned u; } v; v.f = f;
    unsigned r = v.u + 0x7fffu + ((v.u >> 16) & 1u);   // RNE
    return (short)(r >> 16);
}
__device__ __forceinline__ float bf2f(short s) {
    union { unsigned u; float f; } v;
    v.u = ((unsigned)(u16)s) << 16;
    return v.f;
}

// ---------------------------------------------------------------------------
// offsets: off[g] = lower_bound(batch, g)
// ---------------------------------------------------------------------------
__global__ void offsets_kernel(const int* __restrict__ batch, int* __restrict__ off, int N) {
    int g = threadIdx.x;
    if (g > NGR) return;
    int lo = 0, hi = N;
    while (lo < hi) {
        int mid = (lo + hi) >> 1;
        if (batch[mid] < g) lo = mid + 1; else hi = mid;
    }
    off[g] = lo;
}

// ---------------------------------------------------------------------------
// CSR build
// ---------------------------------------------------------------------------
__global__ __launch_bounds__(256)
void deg_kernel(const int* __restrict__ ei, int* __restrict__ deg, int E) {
    int e = blockIdx.x * 256 + threadIdx.x;
    if (e < E) atomicAdd(&deg[ei[E + e]], 1);
}

__global__ __launch_bounds__(1024)
void scan_kernel(const int* __restrict__ deg, int* __restrict__ rowptr, int N) {
    __shared__ int part[1024];
    int t = threadIdx.x;
    int per = (N + 1023) / 1024;
    int a = t * per, b = min(a + per, N);
    int s = 0;
    for (int i = a; i < b; ++i) s += deg[i];
    part[t] = s;
    __syncthreads();
    for (int off = 1; off < 1024; off <<= 1) {
        int v = (t >= off) ? part[t - off] : 0;
        __syncthreads();
        part[t] += v;
        __syncthreads();
    }
    int base = (t == 0) ? 0 : part[t - 1];
    for (int i = a; i < b; ++i) { rowptr[i] = base; base += deg[i]; }
    if (t == 1023) rowptr[N] = base;
}

__global__ __launch_bounds__(256)
void fill_kernel(const int* __restrict__ ei, const int* __restrict__ rowptr,
                 int* __restrict__ cursor, int* __restrict__ col, int E) {
    int e = blockIdx.x * 256 + threadIdx.x;
    if (e >= E) return;
    int src = ei[e];
    int dst = ei[E + e];
    int pos = atomicAdd(&cursor[dst], 1);
    col[rowptr[dst] + pos] = src;
}

// ---------------------------------------------------------------------------
// weight convert: Wt[mat][n (304)][k (320)] = bf16(W[k][n]); pads zero
// ---------------------------------------------------------------------------
__global__ __launch_bounds__(256)
void wcvt_kernel(const float* __restrict__ W1, const float* __restrict__ W2,
                 u16* __restrict__ Wt) {
    int idx = blockIdx.x * 256 + threadIdx.x;
    if (idx >= 10 * KP * 76) return;
    int n4 = idx % 76;
    int k = (idx / 76) % KP;
    int mat = idx / (76 * KP);
    const float* Wsrc = (mat < NL) ? (W1 + (size_t)mat * D * D) : (W2 + (size_t)(mat - NL) * D * D);
    float4 w = make_float4(0.f, 0.f, 0.f, 0.f);
    if (k < D && n4 < 75) w = *(const float4*)(Wsrc + (size_t)k * D + n4 * 4);
    size_t base = ((size_t)mat * 304 + n4 * 4) * KP + k;
    Wt[base]          = (u16)f2bf(w.x);
    Wt[base + KP]     = (u16)f2bf(w.y);
    Wt[base + 2 * KP] = (u16)f2bf(w.z);
    Wt[base + 3 * KP] = (u16)f2bf(w.w);
}

// ---------------------------------------------------------------------------
// x convert: hbf[row][c] = bf16(x[row][c]), pads (c>=300, row>=N) zero
// ---------------------------------------------------------------------------
__global__ __launch_bounds__(256)
void xcvt_kernel(const float* __restrict__ x, u16* __restrict__ hbf, int N) {
    int idx = blockIdx.x * 256 + threadIdx.x;
    if (idx >= NPAD * 40) return;
    int row = idx / 40;
    int c8 = (idx - row * 40) * 8;
    short o[8];
    #pragma unroll
    for (int i = 0; i < 8; ++i) {
        int c = c8 + i;
        float f = (row < N && c < D) ? x[(size_t)row * D + c] : 0.f;
        o[i] = f2bf(f);
    }
    *(bf16x8*)(hbf + (size_t)row * KP + c8) = *(bf16x8*)o;
}

// ---------------------------------------------------------------------------
// gather: zbf[i] = bf16( hbf[i] + sum_{j in N(i)} hbf[j] )  (fp32 accum)
// ---------------------------------------------------------------------------
__global__ __launch_bounds__(256)
void gather_kernel(const u16* __restrict__ H, u16* __restrict__ Z,
                   const int* __restrict__ rowptr, const int* __restrict__ col, int N) {
    int idx = blockIdx.x * 256 + threadIdx.x;
    if (idx >= N * 40) return;
    int node = idx / 40;
    int c8 = (idx - node * 40) * 8;
    int s = rowptr[node], e = rowptr[node + 1];
    bf16x8 v = *(const bf16x8*)(H + (size_t)node * KP + c8);
    float acc[8];
    #pragma unroll
    for (int i = 0; i < 8; ++i) acc[i] = bf2f(v[i]);
    for (int j = s; j < e; ++j) {
        int src = col[j];
        bf16x8 w = *(const bf16x8*)(H + (size_t)src * KP + c8);
        #pragma unroll
        for (int i = 0; i < 8; ++i) acc[i] += bf2f(w[i]);
    }
    short o[8];
    #pragma unroll
    for (int i = 0; i < 8; ++i) o[i] = f2bf(acc[i]);
    *(bf16x8*)(Z + (size_t)node * KP + c8) = *(bf16x8*)o;
}

// ---------------------------------------------------------------------------
// pool, row-major coalesced: one block per graph; 320 thr = 8 row-slices x 40
// bf16x8 col-groups; LDS cross-slice reduce; direct store (no atomics).
// ---------------------------------------------------------------------------
__global__ __launch_bounds__(320)
void pool_kernel(const u16* __restrict__ H, const int* __restrict__ off,
                 float* __restrict__ pooled_l) {
    __shared__ float red[8][KP];
    int t = threadIdx.x;
    int g = blockIdx.x;
    int rq = t / 40;
    int c8 = (t - rq * 40) * 8;
    int r0 = off[g], r1 = off[g + 1];
    float a[8] = {};
    for (int r = r0 + rq; r < r1; r += 8) {
        bf16x8 v = *(const bf16x8*)(H + (size_t)r * KP + c8);
        #pragma unroll
        for (int i = 0; i < 8; ++i) a[i] += bf2f(v[i]);
    }
    #pragma unroll
    for (int i = 0; i < 8; ++i) red[rq][c8 + i] = a[i];
    __syncthreads();
    int c = t;
    if (c < D) {
        float s = 0.f;
        #pragma unroll
        for (int j = 0; j < 8; ++j) s += red[j][c];
        pooled_l[g * D + c] = s;
    }
}

// ---------------------------------------------------------------------------
// MFMA GEMM, barrier-free staging, no LDS in main loop; fused column stats.
// C = op(A) @ W + bias; stats[c] += sum/sumsq over real rows of (acc+bias).
// Block = 4 waves = 256 threads; wave owns 16 rows x 304 cols (19 n-tiles).
// NOTE: all per-column LDS/global loops MUST stride by 256 (block size) —
// round-5 bug: `if (tid<304)` left cols 256..303 uninit and cols 256..299
// never flushed to stats -> var=0 -> 316x blow-up per layer.
// ---------------------------------------------------------------------------
template<bool APPLY>
__global__ __launch_bounds__(256)
void mfma_gemm_kernel(const u16* __restrict__ Abf, const u16* __restrict__ Wt,
                      const float* __restrict__ bias, const float* __restrict__ scsh,
                      u16* __restrict__ Cbf, float* __restrict__ stats, int Nreal) {
    __shared__ float lsum[304], lsq[304];
    const int tid = threadIdx.x;
    for (int c = tid; c < 304; c += 256) { lsum[c] = 0.f; lsq[c] = 0.f; }

    const int wave = tid >> 6, lane = tid & 63;
    const int quad = lane >> 4, l16 = lane & 15;
    const int mBase = blockIdx.x * 64 + wave * 16;

    const u16* arow = Abf + (size_t)(mBase + l16) * KP + quad * 8;
    const u16* wrow = Wt + (size_t)l16 * KP + quad * 8;

    f32x4 acc[19] = {};

    for (int kc = 0; kc < KP; kc += 32) {
        bf16x8 a = *(const bf16x8*)(arow + kc);
        if (APPLY) {
            const float* sp = scsh + kc + quad * 8;
            float4 s0 = *(const float4*)sp;
            float4 s1 = *(const float4*)(sp + 4);
            float4 h0 = *(const float4*)(sp + KP);
            float4 h1 = *(const float4*)(sp + KP + 4);
            float sc[8] = {s0.x, s0.y, s0.z, s0.w, s1.x, s1.y, s1.z, s1.w};
            float sh[8] = {h0.x, h0.y, h0.z, h0.w, h1.x, h1.y, h1.z, h1.w};
            short o[8];
            #pragma unroll
            for (int i = 0; i < 8; ++i)
                o[i] = f2bf(fmaxf(fmaf(bf2f(a[i]), sc[i], sh[i]), 0.f));
            a = *(bf16x8*)o;
        }
        #pragma unroll
        for (int nt = 0; nt < 19; ++nt) {
            bf16x8 b = *(const bf16x8*)(wrow + (size_t)nt * 16 * KP + kc);
            acc[nt] = __builtin_amdgcn_mfma_f32_16x16x32_bf16(a, b, acc[nt], 0, 0, 0);
        }
    }

    __syncthreads();   // lsum/lsq init visible to all waves

    // epilogue: C[row = mBase + quad*4 + r][col = nt*16 + l16] + stats
    const int rbase = mBase + quad * 4;
    #pragma unroll
    for (int nt = 0; nt < 19; ++nt) {
        int colg = nt * 16 + l16;
        if (colg >= D) continue;   // only nt=18, l16>=12 (uniform across quads)
        float bia = bias[colg];
        float s = 0.f, q = 0.f;
        #pragma unroll
        for (int r = 0; r < 4; ++r) {
            int row = rbase + r;
            float v = acc[nt][r] + bia;
            bool ok = row < Nreal;
            if (ok) { s += v; q = fmaf(v, v, q); }
            Cbf[(size_t)row * KP + colg] = ok ? (u16)f2bf(v) : (u16)0;
        }
        // cross-quad reduce within wave (lane bits 4,5); l16 invariant under xor
        s += __shfl_xor(s, 16); s += __shfl_xor(s, 32);
        q += __shfl_xor(q, 16); q += __shfl_xor(q, 32);
        if (quad == 0) { atomicAdd(&lsum[colg], s); atomicAdd(&lsq[colg], q); }
    }
    __syncthreads();
    for (int c = tid; c < D; c += 256) {
        atomAdd(&stats[c], lsum[c]);
        atomAdd(&stats[KP + c], lsq[c]);
    }
}

__global__ void bnfin_kernel(const float* __restrict__ sums, const float* __restrict__ g,
                             const float* __restrict__ be, float* __restrict__ scsh, float invN) {
    int c = threadIdx.x;
    if (c >= D) return;
    float mu = sums[c] * invN;
    float var = sums[KP + c] * invN - mu * mu;
    float s = g[c] / sqrtf(var + BN_EPS);
    scsh[c] = s;
    scsh[KP + c] = fmaf(-mu, s, be[c]);
}

// ---------------------------------------------------------------------------
// BN2 apply + ReLU: hbf = bf16(relu(zbf*scale+shift))
// ---------------------------------------------------------------------------
__global__ __launch_bounds__(256)
void bnapply_kernel(const u16* __restrict__ Z, u16* __restrict__ H,
                    const float* __restrict__ scsh, int N) {
    int idx = blockIdx.x * 256 + threadIdx.x;
    if (idx >= N * 40) return;
    int row = idx / 40;
    int c8 = (idx - row * 40) * 8;
    bf16x8 v = *(const bf16x8*)(Z + (size_t)row * KP + c8);
    const float* sp = scsh + c8;
    float4 s0 = *(const float4*)sp;
    float4 s1 = *(const float4*)(sp + 4);
    float4 h0 = *(const float4*)(sp + KP);
    float4 h1 = *(const float4*)(sp + KP + 4);
    float sc[8] = {s0.x, s0.y, s0.z, s0.w, s1.x, s1.y, s1.z, s1.w};
    float sh[8] = {h0.x, h0.y, h0.z, h0.w, h1.x, h1.y, h1.z, h1.w};
    short o[8];
    #pragma unroll
    for (int i = 0; i < 8; ++i)
        o[i] = f2bf(fmaxf(fmaf(bf2f(v[i]), sc[i], sh[i]), 0.f));
    *(bf16x8*)(H + (size_t)row * KP + c8) = *(bf16x8*)o;
}

// ---------------------------------------------------------------------------
// readout
// ---------------------------------------------------------------------------
__global__ __launch_bounds__(128)
void bias_init_kernel(const float* __restrict__ fcb, float* __restrict__ out) {
    int i = blockIdx.x * 128 + threadIdx.x;
    if (i >= NGR * NC) return;
    int c = i & (NC - 1);
    float s = 0.f;
    for (int l = 0; l <= NL; ++l) s += fcb[l * NC + c];
    out[i] = s;
}

__global__ __launch_bounds__(128)
void readout_kernel(const float* __restrict__ pooled, const int* __restrict__ off,
                    const float* __restrict__ fcW, float* __restrict__ out) {
    __shared__ float sp[4][D];
    int c = threadIdx.x;
    int l = blockIdx.y;
    int g0 = blockIdx.x * 4;
    for (int i = c; i < 4 * D; i += 128) {
        int gg = i / D, k = i - gg * D;
        sp[gg][k] = pooled[((size_t)l * NGR + g0 + gg) * D + k];
    }
    __syncthreads();
    float acc[4] = {0.f, 0.f, 0.f, 0.f};
    for (int k = 0; k < D; ++k) {
        float w = fcW[((size_t)l * D + k) * NC + c];
        #pragma unroll
        for (int gg = 0; gg < 4; ++gg) acc[gg] = fmaf(sp[gg][k], w, acc[gg]);
    }
    #pragma unroll
    for (int gg = 0; gg < 4; ++gg) {
        int g = g0 + gg;
        float inv = 1.0f / fmaxf((float)(off[g + 1] - off[g]), 1.0f);
        atomAdd(&out[g * NC + c], acc[gg] * inv);
    }
}

// ---------------------------------------------------------------------------
extern "C" void kernel_launch(void* const* d_in, const int* in_sizes, int n_in,
                              void* d_out, int out_size, void* d_ws, size_t ws_size,
                              hipStream_t stream) {
    const float* x       = (const float*)d_in[0];
    const int*   ei      = (const int*)d_in[1];
    const int*   batch   = (const int*)d_in[2];
    const float* W1  = (const float*)d_in[3];
    const float* b1  = (const float*)d_in[4];
    const float* g1  = (const float*)d_in[5];
    const float* be1 = (const float*)d_in[6];
    const float* W2  = (const float*)d_in[7];
    const float* b2  = (const float*)d_in[8];
    const float* bng = (const float*)d_in[9];
    const float* bnb = (const float*)d_in[10];
    const float* fcW = (const float*)d_in[11];
    const float* fcb = (const float*)d_in[12];
    float* out = (float*)d_out;

    const int N = in_sizes[0] / D;   // 50000
    const int E = in_sizes[1] / 2;   // 400000

    u16* hbf = (u16*)d_ws;                       // NPAD*KP
    u16* zbf = hbf + (size_t)NPAD * KP;          // NPAD*KP
    u16* Wt  = zbf + (size_t)NPAD * KP;          // 10*304*KP
    float* pooled = (float*)(Wt + (size_t)10 * 304 * KP);    // 6*NGR*D
    float* stats  = pooled + (size_t)(NL + 1) * NGR * D;     // 2*KP
    float* sc1    = stats + 2 * KP;                          // 2*KP
    float* sc2    = sc1 + 2 * KP;                            // 2*KP
    int*   off    = (int*)(sc2 + 2 * KP);                    // NGR+1
    int*   rowptr = off + NGR + 1;                           // N+1
    int*   cursor = rowptr + N + 1;                          // N
    int*   col    = cursor + N;                              // E

    hipMemsetAsync(stats, 0, 6 * KP * sizeof(float), stream);   // stats + sc1 + sc2 pads
    offsets_kernel<<<1, 320, 0, stream>>>(batch, off, N);
    bias_init_kernel<<<(NGR * NC + 127) / 128, 128, 0, stream>>>(fcb, out);

    // ---- CSR build (once) ----
    hipMemsetAsync(cursor, 0, N * sizeof(int), stream);
    deg_kernel<<<(E + 255) / 256, 256, 0, stream>>>(ei, cursor, E);
    scan_kernel<<<1, 1024, 0, stream>>>(cursor, rowptr, N);
    hipMemsetAsync(cursor, 0, N * sizeof(int), stream);
    fill_kernel<<<(E + 255) / 256, 256, 0, stream>>>(ei, rowptr, cursor, col, E);

    // ---- precompute bf16 weights + input ----
    wcvt_kernel<<<(10 * KP * 76 + 255) / 256, 256, 0, stream>>>(W1, W2, Wt);
    xcvt_kernel<<<(NPAD * 40 + 255) / 256, 256, 0, stream>>>(x, hbf, N);

    const int gemm_blocks = NPAD / 64;           // 782
    const int nd40 = N * 40;
    float invN = 1.0f / (float)N;
    const size_t WtM = (size_t)304 * KP;

    for (int l = 0; l < NL; ++l) {
        pool_kernel<<<NGR, 320, 0, stream>>>(hbf, off, pooled + (size_t)l * NGR * D);
        gather_kernel<<<(nd40 + 255) / 256, 256, 0, stream>>>(hbf, zbf, rowptr, col, N);
        // GEMM1 (+stats): zbf @ W1 -> hbf
        hipMemsetAsync(stats, 0, 2 * KP * sizeof(float), stream);
        mfma_gemm_kernel<false><<<gemm_blocks, 256, 0, stream>>>(
            zbf, Wt + (size_t)l * WtM, b1 + l * D, sc1, hbf, stats, N);
        bnfin_kernel<<<1, 320, 0, stream>>>(stats, g1 + l * D, be1 + l * D, sc1, invN);
        // GEMM2 (BN1+ReLU on the fly, +stats): hbf @ W2 -> zbf
        hipMemsetAsync(stats, 0, 2 * KP * sizeof(float), stream);
        mfma_gemm_kernel<true><<<gemm_blocks, 256, 0, stream>>>(
            hbf, Wt + (size_t)(NL + l) * WtM, b2 + l * D, sc1, zbf, stats, N);
        bnfin_kernel<<<1, 320, 0, stream>>>(stats, bng + l * D, bnb + l * D, sc2, invN);
        // BN2+ReLU: zbf -> hbf
        bnapply_kernel<<<(nd40 + 255) / 256, 256, 0, stream>>>(zbf, hbf, sc2, N);
    }
    pool_kernel<<<NGR, 320, 0, stream>>>(hbf, off, pooled + (size_t)NL * NGR * D);
    readout_kernel<<<dim3(NGR / 4, NL + 1), 128, 0, stream>>>(pooled, off, fcW, out);
}

// Round 8
// 1408.514 us; speedup vs baseline: 8.2151x; 1.3253x over previous
//
#include <hip/hip_runtime.h>

#define D 300
#define KP 320
#define NPAD 50048
#define NGR 256
#define NL 5
#define NC 128
#define BN_EPS 1e-5f

typedef __attribute__((ext_vector_type(8))) short bf16x8;
typedef __attribute__((ext_vector_type(4))) float f32x4;
typedef unsigned short u16;

__device__ __forceinline__ void atomAdd(float* p, float v) { unsafeAtomicAdd(p, v); }

__device__ __forceinline__ short f2bf(float f) {
    union { float f; unsigned u; } v; v.f = f;
    unsigned r = v.u + 0x7fffu + ((v.u >> 16) & 1u);   // RNE
    return (short)(r >> 16);
}
__device__ __forceinline__ float bf2f(short s) {
    union { unsigned u; float f; } v;
    v.u = ((unsigned)(u16)s) << 16;
    return v.f;
}

// ---------------------------------------------------------------------------
// offsets: off[g] = lower_bound(batch, g)
// ---------------------------------------------------------------------------
__global__ void offsets_kernel(const int* __restrict__ batch, int* __restrict__ off, int N) {
    int g = threadIdx.x;
    if (g > NGR) return;
    int lo = 0, hi = N;
    while (lo < hi) {
        int mid = (lo + hi) >> 1;
        if (batch[mid] < g) lo = mid + 1; else hi = mid;
    }
    off[g] = lo;
}

// ---------------------------------------------------------------------------
// CSR build
// ---------------------------------------------------------------------------
__global__ __launch_bounds__(256)
void deg_kernel(const int* __restrict__ ei, int* __restrict__ deg, int E) {
    int e = blockIdx.x * 256 + threadIdx.x;
    if (e < E) atomicAdd(&deg[ei[E + e]], 1);
}

__global__ __launch_bounds__(1024)
void scan_kernel(const int* __restrict__ deg, int* __restrict__ rowptr, int N) {
    __shared__ int part[1024];
    int t = threadIdx.x;
    int per = (N + 1023) / 1024;
    int a = t * per, b = min(a + per, N);
    int s = 0;
    for (int i = a; i < b; ++i) s += deg[i];
    part[t] = s;
    __syncthreads();
    for (int off = 1; off < 1024; off <<= 1) {
        int v = (t >= off) ? part[t - off] : 0;
        __syncthreads();
        part[t] += v;
        __syncthreads();
    }
    int base = (t == 0) ? 0 : part[t - 1];
    for (int i = a; i < b; ++i) { rowptr[i] = base; base += deg[i]; }
    if (t == 1023) rowptr[N] = base;
}

__global__ __launch_bounds__(256)
void fill_kernel(const int* __restrict__ ei, const int* __restrict__ rowptr,
                 int* __restrict__ cursor, int* __restrict__ col, int E) {
    int e = blockIdx.x * 256 + threadIdx.x;
    if (e >= E) return;
    int src = ei[e];
    int dst = ei[E + e];
    int pos = atomicAdd(&cursor[dst], 1);
    col[rowptr[dst] + pos] = src;
}

// ---------------------------------------------------------------------------
// weight convert: Wt[mat][n (304)][k (320)] = bf16(W[k][n]); pads zero
// ---------------------------------------------------------------------------
__global__ __launch_bounds__(256)
void wcvt_kernel(const float* __restrict__ W1, const float* __restrict__ W2,
                 u16* __restrict__ Wt) {
    int idx = blockIdx.x * 256 + threadIdx.x;
    if (idx >= 10 * KP * 76) return;
    int n4 = idx % 76;
    int k = (idx / 76) % KP;
    int mat = idx / (76 * KP);
    const float* Wsrc = (mat < NL) ? (W1 + (size_t)mat * D * D) : (W2 + (size_t)(mat - NL) * D * D);
    float4 w = make_float4(0.f, 0.f, 0.f, 0.f);
    if (k < D && n4 < 75) w = *(const float4*)(Wsrc + (size_t)k * D + n4 * 4);
    size_t base = ((size_t)mat * 304 + n4 * 4) * KP + k;
    Wt[base]          = (u16)f2bf(w.x);
    Wt[base + KP]     = (u16)f2bf(w.y);
    Wt[base + 2 * KP] = (u16)f2bf(w.z);
    Wt[base + 3 * KP] = (u16)f2bf(w.w);
}

// ---------------------------------------------------------------------------
// x convert: xbf[row][c] = bf16(x[row][c]), pads (c>=300, row>=N) zero
// ---------------------------------------------------------------------------
__global__ __launch_bounds__(256)
void xcvt_kernel(const float* __restrict__ x, u16* __restrict__ xbf, int N) {
    int idx = blockIdx.x * 256 + threadIdx.x;
    if (idx >= NPAD * 40) return;
    int row = idx / 40;
    int c8 = (idx - row * 40) * 8;
    short o[8];
    #pragma unroll
    for (int i = 0; i < 8; ++i) {
        int c = c8 + i;
        float f = (row < N && c < D) ? x[(size_t)row * D + c] : 0.f;
        o[i] = f2bf(f);
    }
    *(bf16x8*)(xbf + (size_t)row * KP + c8) = *(bf16x8*)o;
}

// ---------------------------------------------------------------------------
// gather with fused BN2+ReLU on the source rows:
//   h(r) = APPLY ? relu(src[r]*sc + sh) : src[r]      (elementwise, fp32)
//   Z[i] = bf16( h(i) + sum_{j in N(i)} h(j) )
// APPLY=false for layer 0 (raw x). Pads stay 0 (sc/sh pads are 0).
// ---------------------------------------------------------------------------
template<bool APPLY>
__global__ __launch_bounds__(256)
void gather_kernel(const u16* __restrict__ H, u16* __restrict__ Z,
                   const int* __restrict__ rowptr, const int* __restrict__ col,
                   const float* __restrict__ scsh, int N) {
    int idx = blockIdx.x * 256 + threadIdx.x;
    if (idx >= N * 40) return;
    int node = idx / 40;
    int c8 = (idx - node * 40) * 8;
    float sc[8], sh[8];
    if (APPLY) {
        #pragma unroll
        for (int i = 0; i < 8; ++i) { sc[i] = scsh[c8 + i]; sh[i] = scsh[KP + c8 + i]; }
    }
    int s = rowptr[node], e = rowptr[node + 1];
    bf16x8 v = *(const bf16x8*)(H + (size_t)node * KP + c8);
    float acc[8];
    #pragma unroll
    for (int i = 0; i < 8; ++i) {
        float f = bf2f(v[i]);
        acc[i] = APPLY ? fmaxf(fmaf(f, sc[i], sh[i]), 0.f) : f;
    }
    for (int j = s; j < e; ++j) {
        int src = col[j];
        bf16x8 w = *(const bf16x8*)(H + (size_t)src * KP + c8);
        #pragma unroll
        for (int i = 0; i < 8; ++i) {
            float f = bf2f(w[i]);
            acc[i] += APPLY ? fmaxf(fmaf(f, sc[i], sh[i]), 0.f) : f;
        }
    }
    short o[8];
    #pragma unroll
    for (int i = 0; i < 8; ++i) o[i] = f2bf(acc[i]);
    *(bf16x8*)(Z + (size_t)node * KP + c8) = *(bf16x8*)o;
}

// ---------------------------------------------------------------------------
// pool with optional fused BN2+ReLU; one block per graph, coalesced rows.
// ---------------------------------------------------------------------------
template<bool APPLY>
__global__ __launch_bounds__(320)
void pool_kernel(const u16* __restrict__ H, const int* __restrict__ off,
                 const float* __restrict__ scsh, float* __restrict__ pooled_l) {
    __shared__ float red[8][KP];
    int t = threadIdx.x;
    int g = blockIdx.x;
    int rq = t / 40;
    int c8 = (t - rq * 40) * 8;
    float sc[8], sh[8];
    if (APPLY) {
        #pragma unroll
        for (int i = 0; i < 8; ++i) { sc[i] = scsh[c8 + i]; sh[i] = scsh[KP + c8 + i]; }
    }
    int r0 = off[g], r1 = off[g + 1];
    float a[8] = {};
    for (int r = r0 + rq; r < r1; r += 8) {
        bf16x8 v = *(const bf16x8*)(H + (size_t)r * KP + c8);
        #pragma unroll
        for (int i = 0; i < 8; ++i) {
            float f = bf2f(v[i]);
            a[i] += APPLY ? fmaxf(fmaf(f, sc[i], sh[i]), 0.f) : f;
        }
    }
    #pragma unroll
    for (int i = 0; i < 8; ++i) red[rq][c8 + i] = a[i];
    __syncthreads();
    int c = t;
    if (c < D) {
        float s = 0.f;
        #pragma unroll
        for (int j = 0; j < 8; ++j) s += red[j][c];
        pooled_l[g * D + c] = s;
    }
}

// ---------------------------------------------------------------------------
// MFMA GEMM, no LDS in main loop; fused column stats.
// Block = 4 waves = 256 thr; wave owns 32 rows (2 a-frags) x 304 cols.
// Each b-frag load feeds 2 MFMAs (round-6 profile: 1 MFMA/load, issue-bound).
// Per-column loops stride by 256 (round-5 bug note).
// ---------------------------------------------------------------------------
template<bool APPLY>
__global__ __launch_bounds__(256)
void mfma_gemm_kernel(const u16* __restrict__ Abf, const u16* __restrict__ Wt,
                      const float* __restrict__ bias, const float* __restrict__ scsh,
                      u16* __restrict__ Cbf, float* __restrict__ stats, int Nreal) {
    __shared__ float lsum[304], lsq[304];
    const int tid = threadIdx.x;
    for (int c = tid; c < 304; c += 256) { lsum[c] = 0.f; lsq[c] = 0.f; }

    const int wave = tid >> 6, lane = tid & 63;
    const int quad = lane >> 4, l16 = lane & 15;
    const int mBase = blockIdx.x * 128 + wave * 32;

    const u16* arow0 = Abf + (size_t)(mBase + l16) * KP + quad * 8;
    const u16* arow1 = arow0 + (size_t)16 * KP;
    const u16* wrow = Wt + (size_t)l16 * KP + quad * 8;

    f32x4 acc[2][19] = {};

    for (int kc = 0; kc < KP; kc += 32) {
        bf16x8 a0 = *(const bf16x8*)(arow0 + kc);
        bf16x8 a1 = *(const bf16x8*)(arow1 + kc);
        if (APPLY) {
            const float* sp = scsh + kc + quad * 8;
            float4 s0 = *(const float4*)sp;
            float4 s1 = *(const float4*)(sp + 4);
            float4 h0 = *(const float4*)(sp + KP);
            float4 h1 = *(const float4*)(sp + KP + 4);
            float sc[8] = {s0.x, s0.y, s0.z, s0.w, s1.x, s1.y, s1.z, s1.w};
            float sh[8] = {h0.x, h0.y, h0.z, h0.w, h1.x, h1.y, h1.z, h1.w};
            short o0[8], o1[8];
            #pragma unroll
            for (int i = 0; i < 8; ++i) {
                o0[i] = f2bf(fmaxf(fmaf(bf2f(a0[i]), sc[i], sh[i]), 0.f));
                o1[i] = f2bf(fmaxf(fmaf(bf2f(a1[i]), sc[i], sh[i]), 0.f));
            }
            a0 = *(bf16x8*)o0;
            a1 = *(bf16x8*)o1;
        }
        #pragma unroll
        for (int nt = 0; nt < 19; ++nt) {
            bf16x8 b = *(const bf16x8*)(wrow + (size_t)nt * 16 * KP + kc);
            acc[0][nt] = __builtin_amdgcn_mfma_f32_16x16x32_bf16(a0, b, acc[0][nt], 0, 0, 0);
            acc[1][nt] = __builtin_amdgcn_mfma_f32_16x16x32_bf16(a1, b, acc[1][nt], 0, 0, 0);
        }
    }

    __syncthreads();   // lsum/lsq init visible to all waves

    // epilogue: C[row = mBase + t*16 + quad*4 + r][col = nt*16 + l16] + stats
    #pragma unroll
    for (int nt = 0; nt < 19; ++nt) {
        int colg = nt * 16 + l16;
        if (colg >= D) continue;   // only nt=18, l16>=12 (uniform across quads)
        float bia = bias[colg];
        float s = 0.f, q = 0.f;
        #pragma unroll
        for (int t = 0; t < 2; ++t) {
            int rbase = mBase + t * 16 + quad * 4;
            #pragma unroll
            for (int r = 0; r < 4; ++r) {
                int row = rbase + r;
                float v = acc[t][nt][r] + bia;
                bool ok = row < Nreal;
                if (ok) { s += v; q = fmaf(v, v, q); }
                Cbf[(size_t)row * KP + colg] = ok ? (u16)f2bf(v) : (u16)0;
            }
        }
        s += __shfl_xor(s, 16); s += __shfl_xor(s, 32);
        q += __shfl_xor(q, 16); q += __shfl_xor(q, 32);
        if (quad == 0) { atomicAdd(&lsum[colg], s); atomicAdd(&lsq[colg], q); }
    }
    __syncthreads();
    for (int c = tid; c < D; c += 256) {
        atomAdd(&stats[c], lsum[c]);
        atomAdd(&stats[KP + c], lsq[c]);
    }
}

__global__ void bnfin_kernel(const float* __restrict__ sums, const float* __restrict__ g,
                             const float* __restrict__ be, float* __restrict__ scsh, float invN) {
    int c = threadIdx.x;
    if (c >= D) return;
    float mu = sums[c] * invN;
    float var = sums[KP + c] * invN - mu * mu;
    float s = g[c] / sqrtf(var + BN_EPS);
    scsh[c] = s;
    scsh[KP + c] = fmaf(-mu, s, be[c]);
}

// ---------------------------------------------------------------------------
// readout
// ---------------------------------------------------------------------------
__global__ __launch_bounds__(128)
void bias_init_kernel(const float* __restrict__ fcb, float* __restrict__ out) {
    int i = blockIdx.x * 128 + threadIdx.x;
    if (i >= NGR * NC) return;
    int c = i & (NC - 1);
    float s = 0.f;
    for (int l = 0; l <= NL; ++l) s += fcb[l * NC + c];
    out[i] = s;
}

__global__ __launch_bounds__(128)
void readout_kernel(const float* __restrict__ pooled, const int* __restrict__ off,
                    const float* __restrict__ fcW, float* __restrict__ out) {
    __shared__ float sp[4][D];
    int c = threadIdx.x;
    int l = blockIdx.y;
    int g0 = blockIdx.x * 4;
    for (int i = c; i < 4 * D; i += 128) {
        int gg = i / D, k = i - gg * D;
        sp[gg][k] = pooled[((size_t)l * NGR + g0 + gg) * D + k];
    }
    __syncthreads();
    float acc[4] = {0.f, 0.f, 0.f, 0.f};
    for (int k = 0; k < D; ++k) {
        float w = fcW[((size_t)l * D + k) * NC + c];
        #pragma unroll
        for (int gg = 0; gg < 4; ++gg) acc[gg] = fmaf(sp[gg][k], w, acc[gg]);
    }
    #pragma unroll
    for (int gg = 0; gg < 4; ++gg) {
        int g = g0 + gg;
        float inv = 1.0f / fmaxf((float)(off[g + 1] - off[g]), 1.0f);
        atomAdd(&out[g * NC + c], acc[gg] * inv);
    }
}

// ---------------------------------------------------------------------------
extern "C" void kernel_launch(void* const* d_in, const int* in_sizes, int n_in,
                              void* d_out, int out_size, void* d_ws, size_t ws_size,
                              hipStream_t stream) {
    const float* x       = (const float*)d_in[0];
    const int*   ei      = (const int*)d_in[1];
    const int*   batch   = (const int*)d_in[2];
    const float* W1  = (const float*)d_in[3];
    const float* b1  = (const float*)d_in[4];
    const float* g1  = (const float*)d_in[5];
    const float* be1 = (const float*)d_in[6];
    const float* W2  = (const float*)d_in[7];
    const float* b2  = (const float*)d_in[8];
    const float* bng = (const float*)d_in[9];
    const float* bnb = (const float*)d_in[10];
    const float* fcW = (const float*)d_in[11];
    const float* fcb = (const float*)d_in[12];
    float* out = (float*)d_out;

    const int N = in_sizes[0] / D;   // 50000
    const int E = in_sizes[1] / 2;   // 400000

    u16* xbf  = (u16*)d_ws;                      // NPAD*KP (read-only after cvt)
    u16* bufA = xbf + (size_t)NPAD * KP;         // NPAD*KP
    u16* bufB = bufA + (size_t)NPAD * KP;        // NPAD*KP
    u16* Wt   = bufB + (size_t)NPAD * KP;        // 10*304*KP
    float* pooled = (float*)(Wt + (size_t)10 * 304 * KP);    // 6*NGR*D
    float* stats  = pooled + (size_t)(NL + 1) * NGR * D;     // 2*KP
    float* sc1    = stats + 2 * KP;                          // 2*KP
    float* sc2    = sc1 + 2 * KP;                            // 2*KP
    int*   off    = (int*)(sc2 + 2 * KP);                    // NGR+1
    int*   rowptr = off + NGR + 1;                           // N+1
    int*   cursor = rowptr + N + 1;                          // N
    int*   col    = cursor + N;                              // E

    hipMemsetAsync(stats, 0, 6 * KP * sizeof(float), stream);   // stats + sc1 + sc2 pads
    offsets_kernel<<<1, 320, 0, stream>>>(batch, off, N);
    bias_init_kernel<<<(NGR * NC + 127) / 128, 128, 0, stream>>>(fcb, out);

    // ---- CSR build (once) ----
    hipMemsetAsync(cursor, 0, N * sizeof(int), stream);
    deg_kernel<<<(E + 255) / 256, 256, 0, stream>>>(ei, cursor, E);
    scan_kernel<<<1, 1024, 0, stream>>>(cursor, rowptr, N);
    hipMemsetAsync(cursor, 0, N * sizeof(int), stream);
    fill_kernel<<<(E + 255) / 256, 256, 0, stream>>>(ei, rowptr, cursor, col, E);

    // ---- precompute bf16 weights + input ----
    wcvt_kernel<<<(10 * KP * 76 + 255) / 256, 256, 0, stream>>>(W1, W2, Wt);
    xcvt_kernel<<<(NPAD * 40 + 255) / 256, 256, 0, stream>>>(x, xbf, N);

    const int gemm_blocks = NPAD / 128;          // 391
    const int nd40 = N * 40;
    float invN = 1.0f / (float)N;
    const size_t WtM = (size_t)304 * KP;

    // pooled[0] = sum of raw x rows per graph
    pool_kernel<false><<<NGR, 320, 0, stream>>>(xbf, off, sc2, pooled);

    u16* g = bufA;
    u16* t = bufB;
    const u16* src = xbf;
    for (int l = 0; l < NL; ++l) {
        // gather (+BN2/ReLU of prev layer for l>0): src -> g
        if (l == 0)
            gather_kernel<false><<<(nd40 + 255) / 256, 256, 0, stream>>>(src, g, rowptr, col, sc2, N);
        else
            gather_kernel<true><<<(nd40 + 255) / 256, 256, 0, stream>>>(src, g, rowptr, col, sc2, N);
        // GEMM1 (+stats): g @ W1 -> t
        hipMemsetAsync(stats, 0, 2 * KP * sizeof(float), stream);
        mfma_gemm_kernel<false><<<gemm_blocks, 256, 0, stream>>>(
            g, Wt + (size_t)l * WtM, b1 + l * D, sc1, t, stats, N);
        bnfin_kernel<<<1, 320, 0, stream>>>(stats, g1 + l * D, be1 + l * D, sc1, invN);
        // GEMM2 (BN1+ReLU on the fly, +stats): t @ W2 -> g   (z_l := g)
        hipMemsetAsync(stats, 0, 2 * KP * sizeof(float), stream);
        mfma_gemm_kernel<true><<<gemm_blocks, 256, 0, stream>>>(
            t, Wt + (size_t)(NL + l) * WtM, b2 + l * D, sc1, g, stats, N);
        bnfin_kernel<<<1, 320, 0, stream>>>(stats, bng + l * D, bnb + l * D, sc2, invN);
        // pooled[l+1] = per-graph sum of relu(bn2(z_l)) via on-the-fly apply
        pool_kernel<true><<<NGR, 320, 0, stream>>>(g, off, sc2, pooled + (size_t)(l + 1) * NGR * D);
        src = g;
        u16* tmp = g; g = t; t = tmp;
    }
    readout_kernel<<<dim3(NGR / 4, NL + 1), 128, 0, stream>>>(pooled, off, fcW, out);
}

// Round 9
// 1318.171 us; speedup vs baseline: 8.7781x; 1.0685x over previous
//
#include <hip/hip_runtime.h>

#define D 300
#define KP 320
#define NPAD 50048
#define NGR 256
#define NL 5
#define NC 128
#define BN_EPS 1e-5f

typedef __attribute__((ext_vector_type(8))) short bf16x8;
typedef __attribute__((ext_vector_type(4))) float f32x4;
typedef unsigned short u16;

__device__ __forceinline__ void atomAdd(float* p, float v) { unsafeAtomicAdd(p, v); }

__device__ __forceinline__ short f2bf(float f) {
    union { float f; unsigned u; } v; v.f = f;
    unsigned r = v.u + 0x7fffu + ((v.u >> 16) & 1u);   // RNE
    return (short)(r >> 16);
}
__device__ __forceinline__ float bf2f(short s) {
    union { unsigned u; float f; } v;
    v.u = ((unsigned)(u16)s) << 16;
    return v.f;
}

// ---------------------------------------------------------------------------
// offsets: off[g] = lower_bound(batch, g)
// ---------------------------------------------------------------------------
__global__ void offsets_kernel(const int* __restrict__ batch, int* __restrict__ off, int N) {
    int g = threadIdx.x;
    if (g > NGR) return;
    int lo = 0, hi = N;
    while (lo < hi) {
        int mid = (lo + hi) >> 1;
        if (batch[mid] < g) lo = mid + 1; else hi = mid;
    }
    off[g] = lo;
}

// ---------------------------------------------------------------------------
// CSR build
// ---------------------------------------------------------------------------
__global__ __launch_bounds__(256)
void deg_kernel(const int* __restrict__ ei, int* __restrict__ deg, int E) {
    int e = blockIdx.x * 256 + threadIdx.x;
    if (e < E) atomicAdd(&deg[ei[E + e]], 1);
}

__global__ __launch_bounds__(1024)
void scan_kernel(const int* __restrict__ deg, int* __restrict__ rowptr, int N) {
    __shared__ int part[1024];
    int t = threadIdx.x;
    int per = (N + 1023) / 1024;
    int a = t * per, b = min(a + per, N);
    int s = 0;
    for (int i = a; i < b; ++i) s += deg[i];
    part[t] = s;
    __syncthreads();
    for (int off = 1; off < 1024; off <<= 1) {
        int v = (t >= off) ? part[t - off] : 0;
        __syncthreads();
        part[t] += v;
        __syncthreads();
    }
    int base = (t == 0) ? 0 : part[t - 1];
    for (int i = a; i < b; ++i) { rowptr[i] = base; base += deg[i]; }
    if (t == 1023) rowptr[N] = base;
}

__global__ __launch_bounds__(256)
void fill_kernel(const int* __restrict__ ei, const int* __restrict__ rowptr,
                 int* __restrict__ cursor, int* __restrict__ col, int E) {
    int e = blockIdx.x * 256 + threadIdx.x;
    if (e >= E) return;
    int src = ei[e];
    int dst = ei[E + e];
    int pos = atomicAdd(&cursor[dst], 1);
    col[rowptr[dst] + pos] = src;
}

// ---------------------------------------------------------------------------
// weight convert: Wt[mat][n (304)][k (320)] = bf16(W[k][n]); pads zero
// ---------------------------------------------------------------------------
__global__ __launch_bounds__(256)
void wcvt_kernel(const float* __restrict__ W1, const float* __restrict__ W2,
                 u16* __restrict__ Wt) {
    int idx = blockIdx.x * 256 + threadIdx.x;
    if (idx >= 10 * KP * 76) return;
    int n4 = idx % 76;
    int k = (idx / 76) % KP;
    int mat = idx / (76 * KP);
    const float* Wsrc = (mat < NL) ? (W1 + (size_t)mat * D * D) : (W2 + (size_t)(mat - NL) * D * D);
    float4 w = make_float4(0.f, 0.f, 0.f, 0.f);
    if (k < D && n4 < 75) w = *(const float4*)(Wsrc + (size_t)k * D + n4 * 4);
    size_t base = ((size_t)mat * 304 + n4 * 4) * KP + k;
    Wt[base]          = (u16)f2bf(w.x);
    Wt[base + KP]     = (u16)f2bf(w.y);
    Wt[base + 2 * KP] = (u16)f2bf(w.z);
    Wt[base + 3 * KP] = (u16)f2bf(w.w);
}

// ---------------------------------------------------------------------------
// x convert: xbf[row][c] = bf16(x[row][c]), pads (c>=300, row>=N) zero
// ---------------------------------------------------------------------------
__global__ __launch_bounds__(256)
void xcvt_kernel(const float* __restrict__ x, u16* __restrict__ xbf, int N) {
    int idx = blockIdx.x * 256 + threadIdx.x;
    if (idx >= NPAD * 40) return;
    int row = idx / 40;
    int c8 = (idx - row * 40) * 8;
    short o[8];
    #pragma unroll
    for (int i = 0; i < 8; ++i) {
        int c = c8 + i;
        float f = (row < N && c < D) ? x[(size_t)row * D + c] : 0.f;
        o[i] = f2bf(f);
    }
    *(bf16x8*)(xbf + (size_t)row * KP + c8) = *(bf16x8*)o;
}

// ---------------------------------------------------------------------------
// gather with fused BN2+ReLU on the source rows:
//   h(r) = APPLY ? relu(src[r]*sc + sh) : src[r]      (elementwise, fp32)
//   Z[i] = bf16( h(i) + sum_{j in N(i)} h(j) )
// ---------------------------------------------------------------------------
template<bool APPLY>
__global__ __launch_bounds__(256)
void gather_kernel(const u16* __restrict__ H, u16* __restrict__ Z,
                   const int* __restrict__ rowptr, const int* __restrict__ col,
                   const float* __restrict__ scsh, int N) {
    int idx = blockIdx.x * 256 + threadIdx.x;
    if (idx >= N * 40) return;
    int node = idx / 40;
    int c8 = (idx - node * 40) * 8;
    float sc[8], sh[8];
    if (APPLY) {
        #pragma unroll
        for (int i = 0; i < 8; ++i) { sc[i] = scsh[c8 + i]; sh[i] = scsh[KP + c8 + i]; }
    }
    int s = rowptr[node], e = rowptr[node + 1];
    bf16x8 v = *(const bf16x8*)(H + (size_t)node * KP + c8);
    float acc[8];
    #pragma unroll
    for (int i = 0; i < 8; ++i) {
        float f = bf2f(v[i]);
        acc[i] = APPLY ? fmaxf(fmaf(f, sc[i], sh[i]), 0.f) : f;
    }
    for (int j = s; j < e; ++j) {
        int src = col[j];
        bf16x8 w = *(const bf16x8*)(H + (size_t)src * KP + c8);
        #pragma unroll
        for (int i = 0; i < 8; ++i) {
            float f = bf2f(w[i]);
            acc[i] += APPLY ? fmaxf(fmaf(f, sc[i], sh[i]), 0.f) : f;
        }
    }
    short o[8];
    #pragma unroll
    for (int i = 0; i < 8; ++i) o[i] = f2bf(acc[i]);
    *(bf16x8*)(Z + (size_t)node * KP + c8) = *(bf16x8*)o;
}

// ---------------------------------------------------------------------------
// pool with optional fused BN2+ReLU; one block per graph, coalesced rows.
// ---------------------------------------------------------------------------
template<bool APPLY>
__global__ __launch_bounds__(320)
void pool_kernel(const u16* __restrict__ H, const int* __restrict__ off,
                 const float* __restrict__ scsh, float* __restrict__ pooled_l) {
    __shared__ float red[8][KP];
    int t = threadIdx.x;
    int g = blockIdx.x;
    int rq = t / 40;
    int c8 = (t - rq * 40) * 8;
    float sc[8], sh[8];
    if (APPLY) {
        #pragma unroll
        for (int i = 0; i < 8; ++i) { sc[i] = scsh[c8 + i]; sh[i] = scsh[KP + c8 + i]; }
    }
    int r0 = off[g], r1 = off[g + 1];
    float a[8] = {};
    for (int r = r0 + rq; r < r1; r += 8) {
        bf16x8 v = *(const bf16x8*)(H + (size_t)r * KP + c8);
        #pragma unroll
        for (int i = 0; i < 8; ++i) {
            float f = bf2f(v[i]);
            a[i] += APPLY ? fmaxf(fmaf(f, sc[i], sh[i]), 0.f) : f;
        }
    }
    #pragma unroll
    for (int i = 0; i < 8; ++i) red[rq][c8 + i] = a[i];
    __syncthreads();
    int c = t;
    if (c < D) {
        float s = 0.f;
        #pragma unroll
        for (int j = 0; j < 8; ++j) s += red[j][c];
        pooled_l[g * D + c] = s;
    }
}

// ---------------------------------------------------------------------------
// MFMA GEMM with LDS-staged B chunk (shared by the block's 4 waves).
// Block = 4 waves = 256 thr, 64 rows; wave = 16 rows x 304 cols (acc[19]).
// Per k-step: stage B[304][32] into LDS (row stride 40 u16 -> 2-way banks,
// free per m136), then each wave: 1 a-global-load + 19 ds_read_b128 + 19 MFMA.
// B global traffic /4 vs round 7; b-load latency ~200cyc L2 -> ~LDS.
// Fused column stats epilogue (per-column loops stride 256 — round-5 bug).
// ---------------------------------------------------------------------------
template<bool APPLY>
__global__ __launch_bounds__(256)
void mfma_gemm_kernel(const u16* __restrict__ Abf, const u16* __restrict__ Wt,
                      const float* __restrict__ bias, const float* __restrict__ scsh,
                      u16* __restrict__ Cbf, float* __restrict__ stats, int Nreal) {
    __shared__ u16 Bs[304 * 40];            // 23.75 KB, [n][k32] stride 40
    __shared__ float lsum[304], lsq[304];
    const int tid = threadIdx.x;
    for (int c = tid; c < 304; c += 256) { lsum[c] = 0.f; lsq[c] = 0.f; }

    const int wave = tid >> 6, lane = tid & 63;
    const int quad = lane >> 4, l16 = lane & 15;
    const int mBase = blockIdx.x * 64 + wave * 16;

    const u16* arow = Abf + (size_t)(mBase + l16) * KP + quad * 8;

    f32x4 acc[19] = {};

    for (int kc = 0; kc < KP; kc += 32) {
        // issue a-load early so it's in flight during staging
        bf16x8 a = *(const bf16x8*)(arow + kc);
        __syncthreads();                    // Bs safe to overwrite
        // stage B chunk: 304 n-rows x 32 k = 1216 16B units, 5 passes x 256 thr
        #pragma unroll
        for (int p = 0; p < 5; ++p) {
            int unit = p * 256 + tid;
            if (unit < 1216) {
                int n = unit >> 2, kq = unit & 3;
                *(bf16x8*)&Bs[n * 40 + kq * 8] =
                    *(const bf16x8*)(Wt + (size_t)n * KP + kc + kq * 8);
            }
        }
        if (APPLY) {
            const float* sp = scsh + kc + quad * 8;
            float4 s0 = *(const float4*)sp;
            float4 s1 = *(const float4*)(sp + 4);
            float4 h0 = *(const float4*)(sp + KP);
            float4 h1 = *(const float4*)(sp + KP + 4);
            float sc[8] = {s0.x, s0.y, s0.z, s0.w, s1.x, s1.y, s1.z, s1.w};
            float sh[8] = {h0.x, h0.y, h0.z, h0.w, h1.x, h1.y, h1.z, h1.w};
            short o[8];
            #pragma unroll
            for (int i = 0; i < 8; ++i)
                o[i] = f2bf(fmaxf(fmaf(bf2f(a[i]), sc[i], sh[i]), 0.f));
            a = *(bf16x8*)o;
        }
        __syncthreads();                    // Bs ready
        #pragma unroll
        for (int nt = 0; nt < 19; ++nt) {
            bf16x8 b = *(const bf16x8*)&Bs[(nt * 16 + l16) * 40 + quad * 8];
            acc[nt] = __builtin_amdgcn_mfma_f32_16x16x32_bf16(a, b, acc[nt], 0, 0, 0);
        }
    }

    // epilogue: C[row = mBase + quad*4 + r][col = nt*16 + l16] + stats
    const int rbase = mBase + quad * 4;
    #pragma unroll
    for (int nt = 0; nt < 19; ++nt) {
        int colg = nt * 16 + l16;
        if (colg >= D) continue;   // only nt=18, l16>=12 (uniform across quads)
        float bia = bias[colg];
        float s = 0.f, q = 0.f;
        #pragma unroll
        for (int r = 0; r < 4; ++r) {
            int row = rbase + r;
            float v = acc[nt][r] + bia;
            bool ok = row < Nreal;
            if (ok) { s += v; q = fmaf(v, v, q); }
            Cbf[(size_t)row * KP + colg] = ok ? (u16)f2bf(v) : (u16)0;
        }
        s += __shfl_xor(s, 16); s += __shfl_xor(s, 32);
        q += __shfl_xor(q, 16); q += __shfl_xor(q, 32);
        if (quad == 0) { atomicAdd(&lsum[colg], s); atomicAdd(&lsq[colg], q); }
    }
    __syncthreads();
    for (int c = tid; c < D; c += 256) {
        atomAdd(&stats[c], lsum[c]);
        atomAdd(&stats[KP + c], lsq[c]);
    }
}

__global__ void bnfin_kernel(const float* __restrict__ sums, const float* __restrict__ g,
                             const float* __restrict__ be, float* __restrict__ scsh, float invN) {
    int c = threadIdx.x;
    if (c >= D) return;
    float mu = sums[c] * invN;
    float var = sums[KP + c] * invN - mu * mu;
    float s = g[c] / sqrtf(var + BN_EPS);
    scsh[c] = s;
    scsh[KP + c] = fmaf(-mu, s, be[c]);
}

// ---------------------------------------------------------------------------
// readout
// ---------------------------------------------------------------------------
__global__ __launch_bounds__(128)
void bias_init_kernel(const float* __restrict__ fcb, float* __restrict__ out) {
    int i = blockIdx.x * 128 + threadIdx.x;
    if (i >= NGR * NC) return;
    int c = i & (NC - 1);
    float s = 0.f;
    for (int l = 0; l <= NL; ++l) s += fcb[l * NC + c];
    out[i] = s;
}

__global__ __launch_bounds__(128)
void readout_kernel(const float* __restrict__ pooled, const int* __restrict__ off,
                    const float* __restrict__ fcW, float* __restrict__ out) {
    __shared__ float sp[4][D];
    int c = threadIdx.x;
    int l = blockIdx.y;
    int g0 = blockIdx.x * 4;
    for (int i = c; i < 4 * D; i += 128) {
        int gg = i / D, k = i - gg * D;
        sp[gg][k] = pooled[((size_t)l * NGR + g0 + gg) * D + k];
    }
    __syncthreads();
    float acc[4] = {0.f, 0.f, 0.f, 0.f};
    for (int k = 0; k < D; ++k) {
        float w = fcW[((size_t)l * D + k) * NC + c];
        #pragma unroll
        for (int gg = 0; gg < 4; ++gg) acc[gg] = fmaf(sp[gg][k], w, acc[gg]);
    }
    #pragma unroll
    for (int gg = 0; gg < 4; ++gg) {
        int g = g0 + gg;
        float inv = 1.0f / fmaxf((float)(off[g + 1] - off[g]), 1.0f);
        atomAdd(&out[g * NC + c], acc[gg] * inv);
    }
}

// ---------------------------------------------------------------------------
extern "C" void kernel_launch(void* const* d_in, const int* in_sizes, int n_in,
                              void* d_out, int out_size, void* d_ws, size_t ws_size,
                              hipStream_t stream) {
    const float* x       = (const float*)d_in[0];
    const int*   ei      = (const int*)d_in[1];
    const int*   batch   = (const int*)d_in[2];
    const float* W1  = (const float*)d_in[3];
    const float* b1  = (const float*)d_in[4];
    const float* g1  = (const float*)d_in[5];
    const float* be1 = (const float*)d_in[6];
    const float* W2  = (const float*)d_in[7];
    const float* b2  = (const float*)d_in[8];
    const float* bng = (const float*)d_in[9];
    const float* bnb = (const float*)d_in[10];
    const float* fcW = (const float*)d_in[11];
    const float* fcb = (const float*)d_in[12];
    float* out = (float*)d_out;

    const int N = in_sizes[0] / D;   // 50000
    const int E = in_sizes[1] / 2;   // 400000

    u16* xbf  = (u16*)d_ws;                      // NPAD*KP (read-only after cvt)
    u16* bufA = xbf + (size_t)NPAD * KP;         // NPAD*KP
    u16* bufB = bufA + (size_t)NPAD * KP;        // NPAD*KP
    u16* Wt   = bufB + (size_t)NPAD * KP;        // 10*304*KP
    float* pooled = (float*)(Wt + (size_t)10 * 304 * KP);    // 6*NGR*D
    float* stats  = pooled + (size_t)(NL + 1) * NGR * D;     // 2*KP
    float* sc1    = stats + 2 * KP;                          // 2*KP
    float* sc2    = sc1 + 2 * KP;                            // 2*KP
    int*   off    = (int*)(sc2 + 2 * KP);                    // NGR+1
    int*   rowptr = off + NGR + 1;                           // N+1
    int*   cursor = rowptr + N + 1;                          // N
    int*   col    = cursor + N;                              // E

    hipMemsetAsync(stats, 0, 6 * KP * sizeof(float), stream);   // stats + sc1 + sc2 pads
    offsets_kernel<<<1, 320, 0, stream>>>(batch, off, N);
    bias_init_kernel<<<(NGR * NC + 127) / 128, 128, 0, stream>>>(fcb, out);

    // ---- CSR build (once) ----
    hipMemsetAsync(cursor, 0, N * sizeof(int), stream);
    deg_kernel<<<(E + 255) / 256, 256, 0, stream>>>(ei, cursor, E);
    scan_kernel<<<1, 1024, 0, stream>>>(cursor, rowptr, N);
    hipMemsetAsync(cursor, 0, N * sizeof(int), stream);
    fill_kernel<<<(E + 255) / 256, 256, 0, stream>>>(ei, rowptr, cursor, col, E);

    // ---- precompute bf16 weights + input ----
    wcvt_kernel<<<(10 * KP * 76 + 255) / 256, 256, 0, stream>>>(W1, W2, Wt);
    xcvt_kernel<<<(NPAD * 40 + 255) / 256, 256, 0, stream>>>(x, xbf, N);

    const int gemm_blocks = NPAD / 64;           // 782 -> 3 blocks/CU
    const int nd40 = N * 40;
    float invN = 1.0f / (float)N;
    const size_t WtM = (size_t)304 * KP;

    // pooled[0] = sum of raw x rows per graph
    pool_kernel<false><<<NGR, 320, 0, stream>>>(xbf, off, sc2, pooled);

    u16* g = bufA;
    u16* t = bufB;
    const u16* src = xbf;
    for (int l = 0; l < NL; ++l) {
        // gather (+BN2/ReLU of prev layer for l>0): src -> g
        if (l == 0)
            gather_kernel<false><<<(nd40 + 255) / 256, 256, 0, stream>>>(src, g, rowptr, col, sc2, N);
        else
            gather_kernel<true><<<(nd40 + 255) / 256, 256, 0, stream>>>(src, g, rowptr, col, sc2, N);
        // GEMM1 (+stats): g @ W1 -> t
        hipMemsetAsync(stats, 0, 2 * KP * sizeof(float), stream);
        mfma_gemm_kernel<false><<<gemm_blocks, 256, 0, stream>>>(
            g, Wt + (size_t)l * WtM, b1 + l * D, sc1, t, stats, N);
        bnfin_kernel<<<1, 320, 0, stream>>>(stats, g1 + l * D, be1 + l * D, sc1, invN);
        // GEMM2 (BN1+ReLU on the fly, +stats): t @ W2 -> g   (z_l := g)
        hipMemsetAsync(stats, 0, 2 * KP * sizeof(float), stream);
        mfma_gemm_kernel<true><<<gemm_blocks, 256, 0, stream>>>(
            t, Wt + (size_t)(NL + l) * WtM, b2 + l * D, sc1, g, stats, N);
        bnfin_kernel<<<1, 320, 0, stream>>>(stats, bng + l * D, bnb + l * D, sc2, invN);
        // pooled[l+1] = per-graph sum of relu(bn2(z_l)) via on-the-fly apply
        pool_kernel<true><<<NGR, 320, 0, stream>>>(g, off, sc2, pooled + (size_t)(l + 1) * NGR * D);
        src = g;
        u16* tmp = g; g = t; t = tmp;
    }
    readout_kernel<<<dim3(NGR / 4, NL + 1), 128, 0, stream>>>(pooled, off, fcW, out);
}

// Round 10
// 1262.693 us; speedup vs baseline: 9.1638x; 1.0439x over previous
//
#include <hip/hip_runtime.h>

#define D 300
#define KP 320
#define NPAD 50048
#define NGR 256
#define NL 5
#define NC 128
#define BN_EPS 1e-5f

typedef __attribute__((ext_vector_type(8))) short bf16x8;
typedef __attribute__((ext_vector_type(4))) float f32x4;
typedef unsigned short u16;

__device__ __forceinline__ void atomAdd(float* p, float v) { unsafeAtomicAdd(p, v); }

__device__ __forceinline__ short f2bf(float f) {
    union { float f; unsigned u; } v; v.f = f;
    unsigned r = v.u + 0x7fffu + ((v.u >> 16) & 1u);   // RNE
    return (short)(r >> 16);
}
__device__ __forceinline__ float bf2f(short s) {
    union { unsigned u; float f; } v;
    v.u = ((unsigned)(u16)s) << 16;
    return v.f;
}

// ---------------------------------------------------------------------------
// offsets: off[g] = lower_bound(batch, g)
// ---------------------------------------------------------------------------
__global__ void offsets_kernel(const int* __restrict__ batch, int* __restrict__ off, int N) {
    int g = threadIdx.x;
    if (g > NGR) return;
    int lo = 0, hi = N;
    while (lo < hi) {
        int mid = (lo + hi) >> 1;
        if (batch[mid] < g) lo = mid + 1; else hi = mid;
    }
    off[g] = lo;
}

// ---------------------------------------------------------------------------
// CSR build: deg histogram -> hierarchical scan (coalesced) -> slot fill
// (round-8 scan_kernel was 78us: 1 block, stride-49 serial loops. Replaced by
//  196-block reduce + 1-block 196-scan + 196-block prefix: ~10us total.)
// ---------------------------------------------------------------------------
__global__ __launch_bounds__(256)
void deg_kernel(const int* __restrict__ ei, int* __restrict__ deg, int E) {
    int e = blockIdx.x * 256 + threadIdx.x;
    if (e < E) atomicAdd(&deg[ei[E + e]], 1);
}

__global__ __launch_bounds__(256)
void degpart_kernel(const int* __restrict__ deg, int* __restrict__ part, int N) {
    int i = blockIdx.x * 256 + threadIdx.x;
    int v = (i < N) ? deg[i] : 0;
    #pragma unroll
    for (int o = 1; o < 64; o <<= 1) v += __shfl_xor(v, o);
    __shared__ int ws[4];
    if ((threadIdx.x & 63) == 0) ws[threadIdx.x >> 6] = v;
    __syncthreads();
    if (threadIdx.x == 0) part[blockIdx.x] = ws[0] + ws[1] + ws[2] + ws[3];
}

__global__ __launch_bounds__(256)
void partscan_kernel(int* __restrict__ part, int nb) {   // 1 block; nb <= 256
    __shared__ int buf[256];
    int t = threadIdx.x;
    int v = (t < nb) ? part[t] : 0;
    buf[t] = v;
    __syncthreads();
    for (int o = 1; o < 256; o <<= 1) {
        int u = (t >= o) ? buf[t - o] : 0;
        __syncthreads();
        buf[t] += u;
        __syncthreads();
    }
    if (t < nb) part[t] = (t == 0) ? 0 : buf[t - 1];   // exclusive
}

__global__ __launch_bounds__(256)
void rowptr_kernel(const int* __restrict__ deg, const int* __restrict__ part,
                   int* __restrict__ rowptr, int N, int E) {
    __shared__ int buf[256];
    int b = blockIdx.x, t = threadIdx.x;
    int i = b * 256 + t;
    int v = (i < N) ? deg[i] : 0;
    buf[t] = v;
    __syncthreads();
    for (int o = 1; o < 256; o <<= 1) {
        int u = (t >= o) ? buf[t - o] : 0;
        __syncthreads();
        buf[t] += u;
        __syncthreads();
    }
    if (i < N) rowptr[i] = part[b] + buf[t] - v;   // exclusive prefix + block base
    if (b == 0 && t == 0) rowptr[N] = E;
}

__global__ __launch_bounds__(256)
void fill_kernel(const int* __restrict__ ei, const int* __restrict__ rowptr,
                 int* __restrict__ cursor, int* __restrict__ col, int E) {
    int e = blockIdx.x * 256 + threadIdx.x;
    if (e >= E) return;
    int src = ei[e];
    int dst = ei[E + e];
    int pos = atomicAdd(&cursor[dst], 1);
    col[rowptr[dst] + pos] = src;
}

// ---------------------------------------------------------------------------
// weight convert: Wt[mat][n (304)][k (320)] = bf16(W[k][n]); pads zero
// ---------------------------------------------------------------------------
__global__ __launch_bounds__(256)
void wcvt_kernel(const float* __restrict__ W1, const float* __restrict__ W2,
                 u16* __restrict__ Wt) {
    int idx = blockIdx.x * 256 + threadIdx.x;
    if (idx >= 10 * KP * 76) return;
    int n4 = idx % 76;
    int k = (idx / 76) % KP;
    int mat = idx / (76 * KP);
    const float* Wsrc = (mat < NL) ? (W1 + (size_t)mat * D * D) : (W2 + (size_t)(mat - NL) * D * D);
    float4 w = make_float4(0.f, 0.f, 0.f, 0.f);
    if (k < D && n4 < 75) w = *(const float4*)(Wsrc + (size_t)k * D + n4 * 4);
    size_t base = ((size_t)mat * 304 + n4 * 4) * KP + k;
    Wt[base]          = (u16)f2bf(w.x);
    Wt[base + KP]     = (u16)f2bf(w.y);
    Wt[base + 2 * KP] = (u16)f2bf(w.z);
    Wt[base + 3 * KP] = (u16)f2bf(w.w);
}

// ---------------------------------------------------------------------------
// x convert: xbf[row][c] = bf16(x[row][c]), pads (c>=300, row>=N) zero
// ---------------------------------------------------------------------------
__global__ __launch_bounds__(256)
void xcvt_kernel(const float* __restrict__ x, u16* __restrict__ xbf, int N) {
    int idx = blockIdx.x * 256 + threadIdx.x;
    if (idx >= NPAD * 40) return;
    int row = idx / 40;
    int c8 = (idx - row * 40) * 8;
    short o[8];
    #pragma unroll
    for (int i = 0; i < 8; ++i) {
        int c = c8 + i;
        float f = (row < N && c < D) ? x[(size_t)row * D + c] : 0.f;
        o[i] = f2bf(f);
    }
    *(bf16x8*)(xbf + (size_t)row * KP + c8) = *(bf16x8*)o;
}

// ---------------------------------------------------------------------------
// gather with fused BN2+ReLU on the source rows:
//   h(r) = APPLY ? relu(src[r]*sc + sh) : src[r]
//   Z[i] = bf16( h(i) + sum_{j in N(i)} h(j) )
// ---------------------------------------------------------------------------
template<bool APPLY>
__global__ __launch_bounds__(256)
void gather_kernel(const u16* __restrict__ H, u16* __restrict__ Z,
                   const int* __restrict__ rowptr, const int* __restrict__ col,
                   const float* __restrict__ scsh, int N) {
    int idx = blockIdx.x * 256 + threadIdx.x;
    if (idx >= N * 40) return;
    int node = idx / 40;
    int c8 = (idx - node * 40) * 8;
    float sc[8], sh[8];
    if (APPLY) {
        #pragma unroll
        for (int i = 0; i < 8; ++i) { sc[i] = scsh[c8 + i]; sh[i] = scsh[KP + c8 + i]; }
    }
    int s = rowptr[node], e = rowptr[node + 1];
    bf16x8 v = *(const bf16x8*)(H + (size_t)node * KP + c8);
    float acc[8];
    #pragma unroll
    for (int i = 0; i < 8; ++i) {
        float f = bf2f(v[i]);
        acc[i] = APPLY ? fmaxf(fmaf(f, sc[i], sh[i]), 0.f) : f;
    }
    for (int j = s; j < e; ++j) {
        int src = col[j];
        bf16x8 w = *(const bf16x8*)(H + (size_t)src * KP + c8);
        #pragma unroll
        for (int i = 0; i < 8; ++i) {
            float f = bf2f(w[i]);
            acc[i] += APPLY ? fmaxf(fmaf(f, sc[i], sh[i]), 0.f) : f;
        }
    }
    short o[8];
    #pragma unroll
    for (int i = 0; i < 8; ++i) o[i] = f2bf(acc[i]);
    *(bf16x8*)(Z + (size_t)node * KP + c8) = *(bf16x8*)o;
}

// ---------------------------------------------------------------------------
// pool with optional fused BN2+ReLU; one block per graph, coalesced rows.
// ---------------------------------------------------------------------------
template<bool APPLY>
__global__ __launch_bounds__(320)
void pool_kernel(const u16* __restrict__ H, const int* __restrict__ off,
                 const float* __restrict__ scsh, float* __restrict__ pooled_l) {
    __shared__ float red[8][KP];
    int t = threadIdx.x;
    int g = blockIdx.x;
    int rq = t / 40;
    int c8 = (t - rq * 40) * 8;
    float sc[8], sh[8];
    if (APPLY) {
        #pragma unroll
        for (int i = 0; i < 8; ++i) { sc[i] = scsh[c8 + i]; sh[i] = scsh[KP + c8 + i]; }
    }
    int r0 = off[g], r1 = off[g + 1];
    float a[8] = {};
    for (int r = r0 + rq; r < r1; r += 8) {
        bf16x8 v = *(const bf16x8*)(H + (size_t)r * KP + c8);
        #pragma unroll
        for (int i = 0; i < 8; ++i) {
            float f = bf2f(v[i]);
            a[i] += APPLY ? fmaxf(fmaf(f, sc[i], sh[i]), 0.f) : f;
        }
    }
    #pragma unroll
    for (int i = 0; i < 8; ++i) red[rq][c8 + i] = a[i];
    __syncthreads();
    int c = t;
    if (c < D) {
        float s = 0.f;
        #pragma unroll
        for (int j = 0; j < 8; ++j) s += red[j][c];
        pooled_l[g * D + c] = s;
    }
}

// ---------------------------------------------------------------------------
// MFMA GEMM, double-buffered LDS B staging: stage chunk i+1 while computing i.
// One barrier per k-step (round 8 had two: stage->barrier->compute->barrier).
// Block = 4 waves, 64 rows; wave = 16 rows x 304 cols (acc[19]).
// Bs row stride 40 u16 -> 2-way bank aliasing (free, m136).
// Fused column-stats epilogue; per-column loops stride 256 (round-5 bug).
// ---------------------------------------------------------------------------
__device__ __forceinline__ void stage_b(u16* __restrict__ dst, const u16* __restrict__ Wt,
                                        int kc, int tid) {
    #pragma unroll
    for (int p = 0; p < 5; ++p) {
        int unit = p * 256 + tid;
        if (unit < 1216) {                    // 304 n-rows x 4 k-quads
            int n = unit >> 2, kq = unit & 3;
            *(bf16x8*)&dst[n * 40 + kq * 8] =
                *(const bf16x8*)(Wt + (size_t)n * KP + kc + kq * 8);
        }
    }
}

template<bool APPLY>
__global__ __launch_bounds__(256)
void mfma_gemm_kernel(const u16* __restrict__ Abf, const u16* __restrict__ Wt,
                      const float* __restrict__ bias, const float* __restrict__ scsh,
                      u16* __restrict__ Cbf, float* __restrict__ stats, int Nreal) {
    __shared__ u16 Bs[2][304 * 40];         // 2 x 23.75 KB
    __shared__ float lsum[304], lsq[304];
    const int tid = threadIdx.x;
    for (int c = tid; c < 304; c += 256) { lsum[c] = 0.f; lsq[c] = 0.f; }

    const int wave = tid >> 6, lane = tid & 63;
    const int quad = lane >> 4, l16 = lane & 15;
    const int mBase = blockIdx.x * 64 + wave * 16;

    const u16* arow = Abf + (size_t)(mBase + l16) * KP + quad * 8;

    stage_b(Bs[0], Wt, 0, tid);

    f32x4 acc[19] = {};
    int p = 0;
    for (int ic = 0; ic < KP / 32; ++ic) {
        const int kc = ic * 32;
        bf16x8 a = *(const bf16x8*)(arow + kc);
        if (APPLY) {
            const float* sp = scsh + kc + quad * 8;
            float4 s0 = *(const float4*)sp;
            float4 s1 = *(const float4*)(sp + 4);
            float4 h0 = *(const float4*)(sp + KP);
            float4 h1 = *(const float4*)(sp + KP + 4);
            float sc[8] = {s0.x, s0.y, s0.z, s0.w, s1.x, s1.y, s1.z, s1.w};
            float sh[8] = {h0.x, h0.y, h0.z, h0.w, h1.x, h1.y, h1.z, h1.w};
            short o[8];
            #pragma unroll
            for (int i = 0; i < 8; ++i)
                o[i] = f2bf(fmaxf(fmaf(bf2f(a[i]), sc[i], sh[i]), 0.f));
            a = *(bf16x8*)o;
        }
        __syncthreads();   // Bs[p] staged (prev iter) + compute on Bs[p^1] done
        if (ic + 1 < KP / 32) stage_b(Bs[p ^ 1], Wt, kc + 32, tid);
        const u16* bp = Bs[p];
        #pragma unroll
        for (int nt = 0; nt < 19; ++nt) {
            bf16x8 b = *(const bf16x8*)&bp[(nt * 16 + l16) * 40 + quad * 8];
            acc[nt] = __builtin_amdgcn_mfma_f32_16x16x32_bf16(a, b, acc[nt], 0, 0, 0);
        }
        p ^= 1;
    }

    // epilogue: C[row = mBase + quad*4 + r][col = nt*16 + l16] + stats
    const int rbase = mBase + quad * 4;
    #pragma unroll
    for (int nt = 0; nt < 19; ++nt) {
        int colg = nt * 16 + l16;
        if (colg >= D) continue;   // only nt=18, l16>=12 (uniform across quads)
        float bia = bias[colg];
        float s = 0.f, q = 0.f;
        #pragma unroll
        for (int r = 0; r < 4; ++r) {
            int row = rbase + r;
            float v = acc[nt][r] + bia;
            bool ok = row < Nreal;
            if (ok) { s += v; q = fmaf(v, v, q); }
            Cbf[(size_t)row * KP + colg] = ok ? (u16)f2bf(v) : (u16)0;
        }
        s += __shfl_xor(s, 16); s += __shfl_xor(s, 32);
        q += __shfl_xor(q, 16); q += __shfl_xor(q, 32);
        if (quad == 0) { atomicAdd(&lsum[colg], s); atomicAdd(&lsq[colg], q); }
    }
    __syncthreads();
    for (int c = tid; c < D; c += 256) {
        atomAdd(&stats[c], lsum[c]);
        atomAdd(&stats[KP + c], lsq[c]);
    }
}

// ---------------------------------------------------------------------------
// BN finalize; self-zeroes stats for the next GEMM (deletes 10 memset launches)
// ---------------------------------------------------------------------------
__global__ void bnfin_kernel(float* __restrict__ sums, const float* __restrict__ g,
                             const float* __restrict__ be, float* __restrict__ scsh, float invN) {
    int c = threadIdx.x;
    if (c >= D) return;
    float mu = sums[c] * invN;
    float var = sums[KP + c] * invN - mu * mu;
    float s = g[c] / sqrtf(var + BN_EPS);
    scsh[c] = s;
    scsh[KP + c] = fmaf(-mu, s, be[c]);
    sums[c] = 0.f;
    sums[KP + c] = 0.f;
}

// ---------------------------------------------------------------------------
// readout
// ---------------------------------------------------------------------------
__global__ __launch_bounds__(128)
void bias_init_kernel(const float* __restrict__ fcb, float* __restrict__ out) {
    int i = blockIdx.x * 128 + threadIdx.x;
    if (i >= NGR * NC) return;
    int c = i & (NC - 1);
    float s = 0.f;
    for (int l = 0; l <= NL; ++l) s += fcb[l * NC + c];
    out[i] = s;
}

__global__ __launch_bounds__(128)
void readout_kernel(const float* __restrict__ pooled, const int* __restrict__ off,
                    const float* __restrict__ fcW, float* __restrict__ out) {
    __shared__ float sp[4][D];
    int c = threadIdx.x;
    int l = blockIdx.y;
    int g0 = blockIdx.x * 4;
    for (int i = c; i < 4 * D; i += 128) {
        int gg = i / D, k = i - gg * D;
        sp[gg][k] = pooled[((size_t)l * NGR + g0 + gg) * D + k];
    }
    __syncthreads();
    float acc[4] = {0.f, 0.f, 0.f, 0.f};
    for (int k = 0; k < D; ++k) {
        float w = fcW[((size_t)l * D + k) * NC + c];
        #pragma unroll
        for (int gg = 0; gg < 4; ++gg) acc[gg] = fmaf(sp[gg][k], w, acc[gg]);
    }
    #pragma unroll
    for (int gg = 0; gg < 4; ++gg) {
        int g = g0 + gg;
        float inv = 1.0f / fmaxf((float)(off[g + 1] - off[g]), 1.0f);
        atomAdd(&out[g * NC + c], acc[gg] * inv);
    }
}

// ---------------------------------------------------------------------------
extern "C" void kernel_launch(void* const* d_in, const int* in_sizes, int n_in,
                              void* d_out, int out_size, void* d_ws, size_t ws_size,
                              hipStream_t stream) {
    const float* x       = (const float*)d_in[0];
    const int*   ei      = (const int*)d_in[1];
    const int*   batch   = (const int*)d_in[2];
    const float* W1  = (const float*)d_in[3];
    const float* b1  = (const float*)d_in[4];
    const float* g1  = (const float*)d_in[5];
    const float* be1 = (const float*)d_in[6];
    const float* W2  = (const float*)d_in[7];
    const float* b2  = (const float*)d_in[8];
    const float* bng = (const float*)d_in[9];
    const float* bnb = (const float*)d_in[10];
    const float* fcW = (const float*)d_in[11];
    const float* fcb = (const float*)d_in[12];
    float* out = (float*)d_out;

    const int N = in_sizes[0] / D;   // 50000
    const int E = in_sizes[1] / 2;   // 400000
    const int nb = (N + 255) / 256;  // 196 scan blocks

    u16* xbf  = (u16*)d_ws;                      // NPAD*KP (read-only after cvt)
    u16* bufA = xbf + (size_t)NPAD * KP;         // NPAD*KP
    u16* bufB = bufA + (size_t)NPAD * KP;        // NPAD*KP
    u16* Wt   = bufB + (size_t)NPAD * KP;        // 10*304*KP
    float* pooled = (float*)(Wt + (size_t)10 * 304 * KP);    // 6*NGR*D
    float* stats  = pooled + (size_t)(NL + 1) * NGR * D;     // 2*KP
    float* sc1    = stats + 2 * KP;                          // 2*KP
    float* sc2    = sc1 + 2 * KP;                            // 2*KP
    int*   off    = (int*)(sc2 + 2 * KP);                    // NGR+1
    int*   rowptr = off + NGR + 1;                           // N+1
    int*   cursor = rowptr + N + 1;                          // N
    int*   col    = cursor + N;                              // E
    int*   part   = col + E;                                 // 256

    hipMemsetAsync(stats, 0, 6 * KP * sizeof(float), stream);   // stats + sc1 + sc2 pads
    offsets_kernel<<<1, 320, 0, stream>>>(batch, off, N);
    bias_init_kernel<<<(NGR * NC + 127) / 128, 128, 0, stream>>>(fcb, out);

    // ---- CSR build (once) ----
    hipMemsetAsync(cursor, 0, N * sizeof(int), stream);
    deg_kernel<<<(E + 255) / 256, 256, 0, stream>>>(ei, cursor, E);
    degpart_kernel<<<nb, 256, 0, stream>>>(cursor, part, N);
    partscan_kernel<<<1, 256, 0, stream>>>(part, nb);
    rowptr_kernel<<<nb, 256, 0, stream>>>(cursor, part, rowptr, N, E);
    hipMemsetAsync(cursor, 0, N * sizeof(int), stream);
    fill_kernel<<<(E + 255) / 256, 256, 0, stream>>>(ei, rowptr, cursor, col, E);

    // ---- precompute bf16 weights + input ----
    wcvt_kernel<<<(10 * KP * 76 + 255) / 256, 256, 0, stream>>>(W1, W2, Wt);
    xcvt_kernel<<<(NPAD * 40 + 255) / 256, 256, 0, stream>>>(x, xbf, N);

    const int gemm_blocks = NPAD / 64;           // 782
    const int nd40 = N * 40;
    float invN = 1.0f / (float)N;
    const size_t WtM = (size_t)304 * KP;

    // pooled[0] = sum of raw x rows per graph
    pool_kernel<false><<<NGR, 320, 0, stream>>>(xbf, off, sc2, pooled);

    u16* g = bufA;
    u16* t = bufB;
    const u16* src = xbf;
    for (int l = 0; l < NL; ++l) {
        // gather (+BN2/ReLU of prev layer for l>0): src -> g
        if (l == 0)
            gather_kernel<false><<<(nd40 + 255) / 256, 256, 0, stream>>>(src, g, rowptr, col, sc2, N);
        else
            gather_kernel<true><<<(nd40 + 255) / 256, 256, 0, stream>>>(src, g, rowptr, col, sc2, N);
        // GEMM1 (+stats): g @ W1 -> t      (stats zeroed by prior bnfin)
        mfma_gemm_kernel<false><<<gemm_blocks, 256, 0, stream>>>(
            g, Wt + (size_t)l * WtM, b1 + l * D, sc1, t, stats, N);
        bnfin_kernel<<<1, 320, 0, stream>>>(stats, g1 + l * D, be1 + l * D, sc1, invN);
        // GEMM2 (BN1+ReLU on the fly, +stats): t @ W2 -> g   (z_l := g)
        mfma_gemm_kernel<true><<<gemm_blocks, 256, 0, stream>>>(
            t, Wt + (size_t)(NL + l) * WtM, b2 + l * D, sc1, g, stats, N);
        bnfin_kernel<<<1, 320, 0, stream>>>(stats, bng + l * D, bnb + l * D, sc2, invN);
        // pooled[l+1] = per-graph sum of relu(bn2(z_l)) via on-the-fly apply
        pool_kernel<true><<<NGR, 320, 0, stream>>>(g, off, sc2, pooled + (size_t)(l + 1) * NGR * D);
        src = g;
        u16* tmp = g; g = t; t = tmp;
    }
    readout_kernel<<<dim3(NGR / 4, NL + 1), 128, 0, stream>>>(pooled, off, fcW, out);
}

// Round 11
// 1096.516 us; speedup vs baseline: 10.5526x; 1.1516x over previous
//
#include <hip/hip_runtime.h>

#define D 300
#define KP 320
#define NPAD 50048
#define NTILES 782      // NPAD/64
#define TPB 4           // row-tiles per gemm block
#define GB 196          // ceil(NTILES/TPB)
#define WSTRIDE 328     // LDS k-stride (u16): 164 words, %32=4 -> 2-way banks (free)
#define NGR 256
#define NL 5
#define NC 128
#define BN_EPS 1e-5f

typedef __attribute__((ext_vector_type(8))) short bf16x8;
typedef __attribute__((ext_vector_type(4))) float f32x4;
typedef unsigned short u16;

__device__ __forceinline__ void atomAdd(float* p, float v) { unsafeAtomicAdd(p, v); }

__device__ __forceinline__ short f2bf(float f) {
    union { float f; unsigned u; } v; v.f = f;
    unsigned r = v.u + 0x7fffu + ((v.u >> 16) & 1u);   // RNE
    return (short)(r >> 16);
}
__device__ __forceinline__ float bf2f(short s) {
    union { unsigned u; float f; } v;
    v.u = ((unsigned)(u16)s) << 16;
    return v.f;
}

// ---------------------------------------------------------------------------
// offsets: off[g] = lower_bound(batch, g)
// ---------------------------------------------------------------------------
__global__ void offsets_kernel(const int* __restrict__ batch, int* __restrict__ off, int N) {
    int g = threadIdx.x;
    if (g > NGR) return;
    int lo = 0, hi = N;
    while (lo < hi) {
        int mid = (lo + hi) >> 1;
        if (batch[mid] < g) lo = mid + 1; else hi = mid;
    }
    off[g] = lo;
}

// ---------------------------------------------------------------------------
// CSR build: deg histogram -> hierarchical scan -> slot fill
// ---------------------------------------------------------------------------
__global__ __launch_bounds__(256)
void deg_kernel(const int* __restrict__ ei, int* __restrict__ deg, int E) {
    int e = blockIdx.x * 256 + threadIdx.x;
    if (e < E) atomicAdd(&deg[ei[E + e]], 1);
}

__global__ __launch_bounds__(256)
void degpart_kernel(const int* __restrict__ deg, int* __restrict__ part, int N) {
    int i = blockIdx.x * 256 + threadIdx.x;
    int v = (i < N) ? deg[i] : 0;
    #pragma unroll
    for (int o = 1; o < 64; o <<= 1) v += __shfl_xor(v, o);
    __shared__ int ws[4];
    if ((threadIdx.x & 63) == 0) ws[threadIdx.x >> 6] = v;
    __syncthreads();
    if (threadIdx.x == 0) part[blockIdx.x] = ws[0] + ws[1] + ws[2] + ws[3];
}

__global__ __launch_bounds__(256)
void partscan_kernel(int* __restrict__ part, int nb) {   // 1 block; nb <= 256
    __shared__ int buf[256];
    int t = threadIdx.x;
    int v = (t < nb) ? part[t] : 0;
    buf[t] = v;
    __syncthreads();
    for (int o = 1; o < 256; o <<= 1) {
        int u = (t >= o) ? buf[t - o] : 0;
        __syncthreads();
        buf[t] += u;
        __syncthreads();
    }
    if (t < nb) part[t] = (t == 0) ? 0 : buf[t - 1];   // exclusive
}

__global__ __launch_bounds__(256)
void rowptr_kernel(const int* __restrict__ deg, const int* __restrict__ part,
                   int* __restrict__ rowptr, int N, int E) {
    __shared__ int buf[256];
    int b = blockIdx.x, t = threadIdx.x;
    int i = b * 256 + t;
    int v = (i < N) ? deg[i] : 0;
    buf[t] = v;
    __syncthreads();
    for (int o = 1; o < 256; o <<= 1) {
        int u = (t >= o) ? buf[t - o] : 0;
        __syncthreads();
        buf[t] += u;
        __syncthreads();
    }
    if (i < N) rowptr[i] = part[b] + buf[t] - v;
    if (b == 0 && t == 0) rowptr[N] = E;
}

__global__ __launch_bounds__(256)
void fill_kernel(const int* __restrict__ ei, const int* __restrict__ rowptr,
                 int* __restrict__ cursor, int* __restrict__ col, int E) {
    int e = blockIdx.x * 256 + threadIdx.x;
    if (e >= E) return;
    int src = ei[e];
    int dst = ei[E + e];
    int pos = atomicAdd(&cursor[dst], 1);
    col[rowptr[dst] + pos] = src;
}

// ---------------------------------------------------------------------------
// weight convert: Wt[mat][n (320)][k (320)] = bf16(W[k][n]); pads zero
// (n padded to 320 so the 4 gemm n-quarters of 80 are uniform)
// ---------------------------------------------------------------------------
__global__ __launch_bounds__(256)
void wcvt_kernel(const float* __restrict__ W1, const float* __restrict__ W2,
                 u16* __restrict__ Wt) {
    int idx = blockIdx.x * 256 + threadIdx.x;
    if (idx >= 10 * KP * 80) return;
    int n4 = idx % 80;
    int k = (idx / 80) % KP;
    int mat = idx / (80 * KP);
    const float* Wsrc = (mat < NL) ? (W1 + (size_t)mat * D * D) : (W2 + (size_t)(mat - NL) * D * D);
    float4 w = make_float4(0.f, 0.f, 0.f, 0.f);
    if (k < D && n4 < 75) w = *(const float4*)(Wsrc + (size_t)k * D + n4 * 4);
    size_t base = ((size_t)mat * 320 + n4 * 4) * KP + k;
    Wt[base]          = (u16)f2bf(w.x);
    Wt[base + KP]     = (u16)f2bf(w.y);
    Wt[base + 2 * KP] = (u16)f2bf(w.z);
    Wt[base + 3 * KP] = (u16)f2bf(w.w);
}

// ---------------------------------------------------------------------------
// x convert: xbf[row][c] = bf16(x[row][c]), pads (c>=300, row>=N) zero
// ---------------------------------------------------------------------------
__global__ __launch_bounds__(256)
void xcvt_kernel(const float* __restrict__ x, u16* __restrict__ xbf, int N) {
    int idx = blockIdx.x * 256 + threadIdx.x;
    if (idx >= NPAD * 40) return;
    int row = idx / 40;
    int c8 = (idx - row * 40) * 8;
    short o[8];
    #pragma unroll
    for (int i = 0; i < 8; ++i) {
        int c = c8 + i;
        float f = (row < N && c < D) ? x[(size_t)row * D + c] : 0.f;
        o[i] = f2bf(f);
    }
    *(bf16x8*)(xbf + (size_t)row * KP + c8) = *(bf16x8*)o;
}

// ---------------------------------------------------------------------------
// gather with fused BN2+ReLU on source rows; edge loop unrolled x2 for MLP.
//   h(r) = APPLY ? relu(src[r]*sc + sh) : src[r]
//   Z[i] = bf16( h(i) + sum_{j in N(i)} h(j) )
// ---------------------------------------------------------------------------
template<bool APPLY>
__global__ __launch_bounds__(256)
void gather_kernel(const u16* __restrict__ H, u16* __restrict__ Z,
                   const int* __restrict__ rowptr, const int* __restrict__ col,
                   const float* __restrict__ scsh, int N) {
    int idx = blockIdx.x * 256 + threadIdx.x;
    if (idx >= N * 40) return;
    int node = idx / 40;
    int c8 = (idx - node * 40) * 8;
    float sc[8], sh[8];
    if (APPLY) {
        #pragma unroll
        for (int i = 0; i < 8; ++i) { sc[i] = scsh[c8 + i]; sh[i] = scsh[KP + c8 + i]; }
    }
    int s = rowptr[node], e = rowptr[node + 1];
    bf16x8 v = *(const bf16x8*)(H + (size_t)node * KP + c8);
    float acc[8];
    #pragma unroll
    for (int i = 0; i < 8; ++i) {
        float f = bf2f(v[i]);
        acc[i] = APPLY ? fmaxf(fmaf(f, sc[i], sh[i]), 0.f) : f;
    }
    int j = s;
    for (; j + 2 <= e; j += 2) {           // 2 row-loads in flight
        int s0 = col[j], s1 = col[j + 1];
        bf16x8 w0 = *(const bf16x8*)(H + (size_t)s0 * KP + c8);
        bf16x8 w1 = *(const bf16x8*)(H + (size_t)s1 * KP + c8);
        #pragma unroll
        for (int i = 0; i < 8; ++i) {
            float f0 = bf2f(w0[i]);
            float f1 = bf2f(w1[i]);
            acc[i] += APPLY ? fmaxf(fmaf(f0, sc[i], sh[i]), 0.f) : f0;
            acc[i] += APPLY ? fmaxf(fmaf(f1, sc[i], sh[i]), 0.f) : f1;
        }
    }
    if (j < e) {
        int s0 = col[j];
        bf16x8 w0 = *(const bf16x8*)(H + (size_t)s0 * KP + c8);
        #pragma unroll
        for (int i = 0; i < 8; ++i) {
            float f0 = bf2f(w0[i]);
            acc[i] += APPLY ? fmaxf(fmaf(f0, sc[i], sh[i]), 0.f) : f0;
        }
    }
    short o[8];
    #pragma unroll
    for (int i = 0; i < 8; ++i) o[i] = f2bf(acc[i]);
    *(bf16x8*)(Z + (size_t)node * KP + c8) = *(bf16x8*)o;
}

// ---------------------------------------------------------------------------
// pool with optional fused BN2+ReLU; one block per graph, coalesced rows.
// ---------------------------------------------------------------------------
template<bool APPLY>
__global__ __launch_bounds__(320)
void pool_kernel(const u16* __restrict__ H, const int* __restrict__ off,
                 const float* __restrict__ scsh, float* __restrict__ pooled_l) {
    __shared__ float red[8][KP];
    int t = threadIdx.x;
    int g = blockIdx.x;
    int rq = t / 40;
    int c8 = (t - rq * 40) * 8;
    float sc[8], sh[8];
    if (APPLY) {
        #pragma unroll
        for (int i = 0; i < 8; ++i) { sc[i] = scsh[c8 + i]; sh[i] = scsh[KP + c8 + i]; }
    }
    int r0 = off[g], r1 = off[g + 1];
    float a[8] = {};
    for (int r = r0 + rq; r < r1; r += 8) {
        bf16x8 v = *(const bf16x8*)(H + (size_t)r * KP + c8);
        #pragma unroll
        for (int i = 0; i < 8; ++i) {
            float f = bf2f(v[i]);
            a[i] += APPLY ? fmaxf(fmaf(f, sc[i], sh[i]), 0.f) : f;
        }
    }
    #pragma unroll
    for (int i = 0; i < 8; ++i) red[rq][c8 + i] = a[i];
    __syncthreads();
    int c = t;
    if (c < D) {
        float s = 0.f;
        #pragma unroll
        for (int j = 0; j < 8; ++j) s += red[j][c];
        pooled_l[g * D + c] = s;
    }
}

// ---------------------------------------------------------------------------
// Persistent-W MFMA GEMM: grid (GB, 4 n-quarters). Block stages its 80x320
// W-slab into LDS ONCE, then processes TPB row-tiles of 64 rows with ZERO
// barriers in the hot loop (round-9 lesson: per-k-step barrier drain is the
// structural stall; 40 barriers -> 2). Wave = 16 rows x 80 cols (acc[5]);
// whole A-row prefetched (10 bf16x8 = 40 VGPRs, all loads in flight).
// LDS k-stride 328 u16 -> 2-way bank aliasing (free, m136).
// Fused column stats; pad cols (>=D) skipped everywhere (zero invariants).
// ---------------------------------------------------------------------------
template<bool APPLY>
__global__ __launch_bounds__(256)
void mfma_gemm_kernel(const u16* __restrict__ Abf, const u16* __restrict__ Wt,
                      const float* __restrict__ bias, const float* __restrict__ scsh,
                      u16* __restrict__ Cbf, float* __restrict__ stats, int Nreal) {
    __shared__ u16 Ws[80 * WSTRIDE];        // 52.5 KB
    __shared__ float lsum[80], lsq[80];
    const int tid = threadIdx.x;
    const int nBase = blockIdx.y * 80;

    // stage W quarter once: 80 n-rows x 320 k = 3200 bf16x8 units
    {
        const u16* src = Wt + (size_t)nBase * KP;
        for (int unit = tid; unit < 80 * 40; unit += 256) {
            int n = unit / 40, kg = unit - n * 40;
            *(bf16x8*)&Ws[n * WSTRIDE + kg * 8] =
                *(const bf16x8*)(src + (size_t)n * KP + kg * 8);
        }
    }
    if (tid < 80) { lsum[tid] = 0.f; lsq[tid] = 0.f; }
    __syncthreads();                        // Ws + stats-init ready (barrier 1 of 2)

    const int wave = tid >> 6, lane = tid & 63;
    const int quad = lane >> 4, l16 = lane & 15;

    for (int t = 0; t < TPB; ++t) {
        const int tile = blockIdx.x * TPB + t;
        if (tile >= NTILES) break;          // uniform across block
        const int mBase = tile * 64 + wave * 16;
        const u16* arow = Abf + (size_t)(mBase + l16) * KP + quad * 8;

        bf16x8 a[10];
        #pragma unroll
        for (int kc = 0; kc < 10; ++kc) a[kc] = *(const bf16x8*)(arow + kc * 32);
        if (APPLY) {
            #pragma unroll
            for (int kc = 0; kc < 10; ++kc) {
                const float* sp = scsh + kc * 32 + quad * 8;
                float4 s0 = *(const float4*)sp;
                float4 s1 = *(const float4*)(sp + 4);
                float4 h0 = *(const float4*)(sp + KP);
                float4 h1 = *(const float4*)(sp + KP + 4);
                float sc[8] = {s0.x, s0.y, s0.z, s0.w, s1.x, s1.y, s1.z, s1.w};
                float sh[8] = {h0.x, h0.y, h0.z, h0.w, h1.x, h1.y, h1.z, h1.w};
                short o[8];
                #pragma unroll
                for (int i = 0; i < 8; ++i)
                    o[i] = f2bf(fmaxf(fmaf(bf2f(a[kc][i]), sc[i], sh[i]), 0.f));
                a[kc] = *(bf16x8*)o;
            }
        }

        f32x4 acc[5] = {};
        #pragma unroll
        for (int kc = 0; kc < 10; ++kc) {
            #pragma unroll
            for (int nt = 0; nt < 5; ++nt) {
                bf16x8 b = *(const bf16x8*)&Ws[(nt * 16 + l16) * WSTRIDE + kc * 32 + quad * 8];
                acc[nt] = __builtin_amdgcn_mfma_f32_16x16x32_bf16(a[kc], b, acc[nt], 0, 0, 0);
            }
        }

        // epilogue: C[row=mBase+quad*4+r][col=nBase+nt*16+l16] + local stats
        const int rbase = mBase + quad * 4;
        #pragma unroll
        for (int nt = 0; nt < 5; ++nt) {
            int nl = nt * 16 + l16;
            int colg = nBase + nl;
            if (colg >= D) continue;
            float bia = bias[colg];
            float s = 0.f, q = 0.f;
            #pragma unroll
            for (int r = 0; r < 4; ++r) {
                int row = rbase + r;
                float v = acc[nt][r] + bia;
                bool ok = row < Nreal;
                if (ok) { s += v; q = fmaf(v, v, q); }
                Cbf[(size_t)row * KP + colg] = ok ? (u16)f2bf(v) : (u16)0;
            }
            s += __shfl_xor(s, 16); s += __shfl_xor(s, 32);
            q += __shfl_xor(q, 16); q += __shfl_xor(q, 32);
            if (quad == 0) { atomicAdd(&lsum[nl], s); atomicAdd(&lsq[nl], q); }
        }
    }
    __syncthreads();                        // barrier 2 of 2
    if (tid < 80) {
        int colg = nBase + tid;
        if (colg < D) {
            atomAdd(&stats[colg], lsum[tid]);
            atomAdd(&stats[KP + colg], lsq[tid]);
        }
    }
}

// ---------------------------------------------------------------------------
// BN finalize; self-zeroes stats for the next GEMM
// ---------------------------------------------------------------------------
__global__ void bnfin_kernel(float* __restrict__ sums, const float* __restrict__ g,
                             const float* __restrict__ be, float* __restrict__ scsh, float invN) {
    int c = threadIdx.x;
    if (c >= D) return;
    float mu = sums[c] * invN;
    float var = sums[KP + c] * invN - mu * mu;
    float s = g[c] / sqrtf(var + BN_EPS);
    scsh[c] = s;
    scsh[KP + c] = fmaf(-mu, s, be[c]);
    sums[c] = 0.f;
    sums[KP + c] = 0.f;
}

// ---------------------------------------------------------------------------
// readout
// ---------------------------------------------------------------------------
__global__ __launch_bounds__(128)
void bias_init_kernel(const float* __restrict__ fcb, float* __restrict__ out) {
    int i = blockIdx.x * 128 + threadIdx.x;
    if (i >= NGR * NC) return;
    int c = i & (NC - 1);
    float s = 0.f;
    for (int l = 0; l <= NL; ++l) s += fcb[l * NC + c];
    out[i] = s;
}

__global__ __launch_bounds__(128)
void readout_kernel(const float* __restrict__ pooled, const int* __restrict__ off,
                    const float* __restrict__ fcW, float* __restrict__ out) {
    __shared__ float sp[4][D];
    int c = threadIdx.x;
    int l = blockIdx.y;
    int g0 = blockIdx.x * 4;
    for (int i = c; i < 4 * D; i += 128) {
        int gg = i / D, k = i - gg * D;
        sp[gg][k] = pooled[((size_t)l * NGR + g0 + gg) * D + k];
    }
    __syncthreads();
    float acc[4] = {0.f, 0.f, 0.f, 0.f};
    for (int k = 0; k < D; ++k) {
        float w = fcW[((size_t)l * D + k) * NC + c];
        #pragma unroll
        for (int gg = 0; gg < 4; ++gg) acc[gg] = fmaf(sp[gg][k], w, acc[gg]);
    }
    #pragma unroll
    for (int gg = 0; gg < 4; ++gg) {
        int g = g0 + gg;
        float inv = 1.0f / fmaxf((float)(off[g + 1] - off[g]), 1.0f);
        atomAdd(&out[g * NC + c], acc[gg] * inv);
    }
}

// ---------------------------------------------------------------------------
extern "C" void kernel_launch(void* const* d_in, const int* in_sizes, int n_in,
                              void* d_out, int out_size, void* d_ws, size_t ws_size,
                              hipStream_t stream) {
    const float* x       = (const float*)d_in[0];
    const int*   ei      = (const int*)d_in[1];
    const int*   batch   = (const int*)d_in[2];
    const float* W1  = (const float*)d_in[3];
    const float* b1  = (const float*)d_in[4];
    const float* g1  = (const float*)d_in[5];
    const float* be1 = (const float*)d_in[6];
    const float* W2  = (const float*)d_in[7];
    const float* b2  = (const float*)d_in[8];
    const float* bng = (const float*)d_in[9];
    const float* bnb = (const float*)d_in[10];
    const float* fcW = (const float*)d_in[11];
    const float* fcb = (const float*)d_in[12];
    float* out = (float*)d_out;

    const int N = in_sizes[0] / D;   // 50000
    const int E = in_sizes[1] / 2;   // 400000
    const int nb = (N + 255) / 256;  // scan blocks

    u16* xbf  = (u16*)d_ws;                      // NPAD*KP
    u16* bufA = xbf + (size_t)NPAD * KP;         // NPAD*KP
    u16* bufB = bufA + (size_t)NPAD * KP;        // NPAD*KP
    u16* Wt   = bufB + (size_t)NPAD * KP;        // 10*320*KP
    float* pooled = (float*)(Wt + (size_t)10 * 320 * KP);    // 6*NGR*D
    float* stats  = pooled + (size_t)(NL + 1) * NGR * D;     // 2*KP
    float* sc1    = stats + 2 * KP;                          // 2*KP
    float* sc2    = sc1 + 2 * KP;                            // 2*KP
    int*   off    = (int*)(sc2 + 2 * KP);                    // NGR+1
    int*   rowptr = off + NGR + 1;                           // N+1
    int*   cursor = rowptr + N + 1;                          // N
    int*   col    = cursor + N;                              // E
    int*   part   = col + E;                                 // 256

    hipMemsetAsync(stats, 0, 6 * KP * sizeof(float), stream);   // stats + sc1 + sc2 pads
    offsets_kernel<<<1, 320, 0, stream>>>(batch, off, N);
    bias_init_kernel<<<(NGR * NC + 127) / 128, 128, 0, stream>>>(fcb, out);

    // ---- CSR build (once) ----
    hipMemsetAsync(cursor, 0, N * sizeof(int), stream);
    deg_kernel<<<(E + 255) / 256, 256, 0, stream>>>(ei, cursor, E);
    degpart_kernel<<<nb, 256, 0, stream>>>(cursor, part, N);
    partscan_kernel<<<1, 256, 0, stream>>>(part, nb);
    rowptr_kernel<<<nb, 256, 0, stream>>>(cursor, part, rowptr, N, E);
    hipMemsetAsync(cursor, 0, N * sizeof(int), stream);
    fill_kernel<<<(E + 255) / 256, 256, 0, stream>>>(ei, rowptr, cursor, col, E);

    // ---- precompute bf16 weights + input ----
    wcvt_kernel<<<(10 * KP * 80 + 255) / 256, 256, 0, stream>>>(W1, W2, Wt);
    xcvt_kernel<<<(NPAD * 40 + 255) / 256, 256, 0, stream>>>(x, xbf, N);

    const dim3 gemm_grid(GB, 4);
    const int nd40 = N * 40;
    float invN = 1.0f / (float)N;
    const size_t WtM = (size_t)320 * KP;

    // pooled[0] = sum of raw x rows per graph
    pool_kernel<false><<<NGR, 320, 0, stream>>>(xbf, off, sc2, pooled);

    u16* g = bufA;
    u16* t = bufB;
    const u16* src = xbf;
    for (int l = 0; l < NL; ++l) {
        // gather (+BN2/ReLU of prev layer for l>0): src -> g
        if (l == 0)
            gather_kernel<false><<<(nd40 + 255) / 256, 256, 0, stream>>>(src, g, rowptr, col, sc2, N);
        else
            gather_kernel<true><<<(nd40 + 255) / 256, 256, 0, stream>>>(src, g, rowptr, col, sc2, N);
        // GEMM1 (+stats): g @ W1 -> t      (stats zeroed by prior bnfin)
        mfma_gemm_kernel<false><<<gemm_grid, 256, 0, stream>>>(
            g, Wt + (size_t)l * WtM, b1 + l * D, sc1, t, stats, N);
        bnfin_kernel<<<1, 320, 0, stream>>>(stats, g1 + l * D, be1 + l * D, sc1, invN);
        // GEMM2 (BN1+ReLU on the fly, +stats): t @ W2 -> g   (z_l := g)
        mfma_gemm_kernel<true><<<gemm_grid, 256, 0, stream>>>(
            t, Wt + (size_t)(NL + l) * WtM, b2 + l * D, sc1, g, stats, N);
        bnfin_kernel<<<1, 320, 0, stream>>>(stats, bng + l * D, bnb + l * D, sc2, invN);
        // pooled[l+1] = per-graph sum of relu(bn2(z_l)) via on-the-fly apply
        pool_kernel<true><<<NGR, 320, 0, stream>>>(g, off, sc2, pooled + (size_t)(l + 1) * NGR * D);
        src = g;
        u16* tmp = g; g = t; t = tmp;
    }
    readout_kernel<<<dim3(NGR / 4, NL + 1), 128, 0, stream>>>(pooled, off, fcW, out);
}